// Round 8
// baseline (707.013 us; speedup 1.0000x reference)
//
#include <hip/hip_runtime.h>

typedef __bf16 bf16x8 __attribute__((ext_vector_type(8)));
typedef float f32x4 __attribute__((ext_vector_type(4)));
typedef unsigned short u16;
typedef unsigned int u32;
typedef u16 u16x8 __attribute__((ext_vector_type(8)));
typedef u16 u16x4 __attribute__((ext_vector_type(4)));

// B=16, SV=1024, ST=512, D=768, H=8, DH=96. Chunked over CH batches,
// R = CH*1536 rows (CH*1024 visual then CH*512 text).

__device__ __forceinline__ u16 f2bf(float f) {
    u32 u = __builtin_bit_cast(u32, f);
    u32 r = u + 0x7FFFu + ((u >> 16) & 1u);
    return (u16)(r >> 16);
}

__device__ __forceinline__ f32x4 mfma16(bf16x8 a, bf16x8 b, f32x4 c) {
    return __builtin_amdgcn_mfma_f32_16x16x32_bf16(a, b, c, 0, 0, 0);
}

#define GLOAD_LDS16(g, l) __builtin_amdgcn_global_load_lds( \
    (__attribute__((address_space(1))) void*)(g), \
    (__attribute__((address_space(3))) void*)(l), 16, 0, 0)

// ---------- prep kernels ----------

__global__ __launch_bounds__(256) void k_cvt_x(const float* __restrict__ vf,
                                               const float* __restrict__ tf,
                                               u16* __restrict__ X, int nvis4) {
    int i = blockIdx.x * 256 + threadIdx.x;
    f32x4 v = (i < nvis4) ? ((const f32x4*)vf)[i] : ((const f32x4*)tf)[i - nvis4];
    u16x4 o = { f2bf(v[0]), f2bf(v[1]), f2bf(v[2]), f2bf(v[3]) };
    ((u16x4*)X)[i] = o;
}

// src f32 [K0][N0] -> dst bf16 [N0][K0]   (64x64 LDS tiles)
__global__ __launch_bounds__(256) void k_transpose(const float* __restrict__ src,
                                                   u16* __restrict__ dst,
                                                   int K0, int N0) {
    __shared__ float t[64][65];
    int ntx = N0 >> 6;
    int k0 = (blockIdx.x / ntx) << 6, n0 = (blockIdx.x % ntx) << 6;
    int c = threadIdx.x & 63, rr = threadIdx.x >> 6;
#pragma unroll
    for (int q = 0; q < 16; q++) {
        int r = q * 4 + rr;
        t[r][c] = src[(size_t)(k0 + r) * N0 + n0 + c];
    }
    __syncthreads();
#pragma unroll
    for (int q = 0; q < 16; q++) {
        int r = q * 4 + rr;
        dst[(size_t)(n0 + r) * K0 + k0 + c] = f2bf(t[c][r]);
    }
}

__global__ __launch_bounds__(256) void k_bias(const float* __restrict__ bq,
                                              const float* __restrict__ bk,
                                              const float* __restrict__ bv,
                                              float* __restrict__ bqkv) {
    int n = blockIdx.x * 256 + threadIdx.x;
    if (n < 2304) {
        const float* s = (n < 768) ? bq : ((n < 1536) ? bk : bv);
        int r = (n < 768) ? n : ((n < 1536) ? n - 768 : n - 1536);
        bqkv[n] = s[r];
    }
}

__global__ __launch_bounds__(256) void k_zero(float* __restrict__ p) {
    p[blockIdx.x * 256 + threadIdx.x] = 0.f;
}

// ---------- V global transpose: QKV V-cols [R][768] -> VtG [768][R] bf16 ----------
__global__ __launch_bounds__(256) void k_vtrans(const u16* __restrict__ qkv,
                                                u16* __restrict__ VtG, int Rtot) {
    __shared__ alignas(16) u16 t[64][72];
    const int kt = blockIdx.x / 12, dt = blockIdx.x % 12;
    const int k0 = kt << 6, d0 = dt << 6;
    const int tid = threadIdx.x;
#pragma unroll
    for (int it = 0; it < 2; it++) {
        int c = it * 256 + tid;
        int r = c >> 3, cc = c & 7;
        u16x8 v = *(const u16x8*)&qkv[(size_t)(k0 + r) * 2304 + 1536 + d0 + cc * 8];
        *(u16x8*)&t[r][cc * 8] = v;
    }
    __syncthreads();
#pragma unroll
    for (int it = 0; it < 2; it++) {
        int c = it * 256 + tid;
        int k8 = c & 7, d = c >> 3;
        u16x8 o;
#pragma unroll
        for (int e = 0; e < 8; e++) o[e] = t[k8 * 8 + e][d];
        *(u16x8*)&VtG[(size_t)(d0 + d) * Rtot + k0 + k8 * 8] = o;
    }
}

// ---------- GEMM: C[R][N] = A[R][K] * Bt[N][K]^T + bias (+residual) ----------
// XCD-chunked blockIdx swizzle (grid always a multiple of 8).
template <bool OUT_BF16, bool ADD_RES>
__global__ __launch_bounds__(256) void k_gemm(const u16* __restrict__ A,
                                              const u16* __restrict__ Bt,
                                              const float* __restrict__ bias,
                                              const float* __restrict__ resA,
                                              const float* __restrict__ resB,
                                              void* __restrict__ Cout,
                                              int Ndim, int Kdim, int mvisL) {
    __shared__ alignas(16) u16 sA[128 * 32];
    __shared__ alignas(16) u16 sB[128 * 32];
    const int tid = threadIdx.x, wid = tid >> 6, lane = tid & 63;
    const int nwg = gridDim.x;
    const int wg = (blockIdx.x & 7) * (nwg >> 3) + (blockIdx.x >> 3);
    const int ntiles = Ndim >> 7;
    const int mt = wg / ntiles, nt = wg - mt * ntiles;
    const int m0 = mt << 7, n0 = nt << 7;
    const int wm = wid >> 1, wn = wid & 1;
    f32x4 acc[4][4] = {};

    const int r0 = tid >> 2, p0 = tid & 3;
    const int r1 = 64 + (tid >> 2);
    const u16* ga0 = A + (size_t)(m0 + r0) * Kdim + p0 * 8;
    const u16* ga1 = A + (size_t)(m0 + r1) * Kdim + p0 * 8;
    const u16* gb0 = Bt + (size_t)(n0 + r0) * Kdim + p0 * 8;
    const u16* gb1 = Bt + (size_t)(n0 + r1) * Kdim + p0 * 8;
    u16* lA0 = sA + (wid * 64) * 8;
    u16* lA1 = sA + (256 + wid * 64) * 8;
    u16* lB0 = sB + (wid * 64) * 8;
    u16* lB1 = sB + (256 + wid * 64) * 8;

    const int arow = (wm << 6) + (lane & 15);
    const int brow = (wn << 6) + (lane & 15);
    const int kg = (lane >> 4) * 8;

    for (int kt = 0; kt < Kdim; kt += 32) {
        GLOAD_LDS16(ga0 + kt, lA0);
        GLOAD_LDS16(ga1 + kt, lA1);
        GLOAD_LDS16(gb0 + kt, lB0);
        GLOAD_LDS16(gb1 + kt, lB1);
        __syncthreads();
        bf16x8 av[4], bw[4];
#pragma unroll
        for (int i = 0; i < 4; i++) av[i] = *(const bf16x8*)&sA[(arow + i * 16) * 32 + kg];
#pragma unroll
        for (int j = 0; j < 4; j++) bw[j] = *(const bf16x8*)&sB[(brow + j * 16) * 32 + kg];
#pragma unroll
        for (int i = 0; i < 4; i++)
#pragma unroll
            for (int j = 0; j < 4; j++) acc[i][j] = mfma16(av[i], bw[j], acc[i][j]);
        __syncthreads();
    }

    const int col0 = n0 + (wn << 6) + (lane & 15);
    const int rowb = m0 + (wm << 6) + ((lane >> 4) << 2);
    float bvals[4];
#pragma unroll
    for (int j = 0; j < 4; j++) bvals[j] = bias[col0 + j * 16];
#pragma unroll
    for (int i = 0; i < 4; i++) {
#pragma unroll
        for (int rg = 0; rg < 4; rg++) {
            const int row = rowb + i * 16 + rg;
            const float* rp = nullptr;
            if constexpr (ADD_RES)
                rp = (row < mvisL) ? resA + (size_t)row * 768
                                   : resB + (size_t)(row - mvisL) * 768;
#pragma unroll
            for (int j = 0; j < 4; j++) {
                const int col = col0 + j * 16;
                float v = acc[i][j][rg] + bvals[j];
                if constexpr (ADD_RES) v += rp[col];
                if constexpr (OUT_BF16)
                    ((u16*)Cout)[(size_t)row * Ndim + col] = f2bf(v);
                else
                    ((float*)Cout)[(size_t)row * Ndim + col] = v;
            }
        }
    }
}

// ---------- fused cross-attention ----------
// KVBLK=64, 512 blocks (2 per (b,h,dir)), LDS 76.5KB -> 2 blocks/CU = 16 waves.
// Per step: barA -> issue V(cur)+K(next) -> QK^T (j-outer, shared K reads) ->
// softmax both q-sets -> barB (V ready) -> PV (j6-outer, shared V reads).
__global__ __launch_bounds__(512, 4) void k_attn(const u16* __restrict__ qkv,
                                                 const u16* __restrict__ VtG,
                                                 const int* __restrict__ vmaskc,
                                                 const int* __restrict__ tmaskc,
                                                 u16* __restrict__ attn, int CHn, int Rtot) {
    __shared__ alignas(16) u16 Kl[2][64 * 128];   // 32 KB (dbuf)
    __shared__ alignas(16) u16 Vt[96 * 64];       // 12 KB (single)
    __shared__ alignas(16) u16 Pl[2][8][16 * 64]; // 32 KB (both q-sets)
    __shared__ float mk[2][64];

    const int bx = blockIdx.x;
    int b, h, half, qbase, kbase, npass, ntl;
    const int* mask;
    const int vcap = CHn * 16;
    if (bx < vcap) {   // visual q -> text kv: 2 passes x 256 rows, Sk=512
        b = bx >> 4; h = (bx >> 1) & 7; half = bx & 1;
        qbase = (b << 10) + half * 512;
        kbase = (CHn << 10) + (b << 9);
        mask = tmaskc + (b << 9); npass = 2; ntl = 3;   // ntile=8
    } else {           // text q -> visual kv: 1 pass x 256 rows, Sk=1024
        const int bx2 = bx - vcap;
        b = bx2 >> 4; h = (bx2 >> 1) & 7; half = bx2 & 1;
        qbase = (CHn << 10) + (b << 9) + half * 256;
        kbase = b << 10;
        mask = vmaskc + (b << 10); npass = 1; ntl = 4;  // ntile=16
    }
    const int ntile = 1 << ntl;
    const int nsteps = npass << ntl;   // 16 both ways
    const int tid = threadIdx.x, wid = tid >> 6, lane = tid & 63;
    const int l15 = lane & 15, l4 = lane >> 4;
    const float scale = 0.10206207261596577f;  // 1/sqrt(96)

    auto kt_of = [&](int s) {
        const int p = s >> ntl, ktr = s & (ntile - 1);
        return (p & 1) ? (ntile - 1 - ktr) : ktr;    // serpentine
    };
    auto stageK = [&](int kt, int pb) {
#pragma unroll
        for (int it = 0; it < 2; ++it) {             // 1024 chunks of 16B
            const int c = it * 512 + tid;
            const int r = c >> 4, s8 = c & 15;
            const int k8 = s8 ^ (r & 7);
            const u16* src = qkv + (size_t)(kbase + (kt << 6) + r) * 2304 + 768 + h * 96
                             + (k8 < 12 ? k8 * 8 : 0);
            GLOAD_LDS16(src, &Kl[pb][(size_t)c * 8]);
        }
        if (tid < 64) mk[pb][tid] = mask[(kt << 6) + tid] ? 0.f : -1e30f;
    };
    auto stageV = [&](int kt) {
#pragma unroll
        for (int it = 0; it < 2; ++it) {             // 768 chunks of 16B
            const int c = it * 512 + tid;
            if (c < 768) {
                const int d = c >> 3, s8 = c & 7;
                const int k8 = s8 ^ (d & 7);
                const u16* src = VtG + (size_t)(h * 96 + d) * Rtot + kbase + (kt << 6) + k8 * 8;
                GLOAD_LDS16(src, &Vt[(size_t)c * 8]);
            }
        }
    };

    stageK(kt_of(0), 0);
    int s = 0;
    for (int pass = 0; pass < npass; ++pass) {
        const int qbaseP = qbase + pass * 256;
        bf16x8 aq[2][3];
#pragma unroll
        for (int qs = 0; qs < 2; ++qs) {
            const int qr = qbaseP + (wid << 5) + qs * 16 + l15;
#pragma unroll
            for (int kk = 0; kk < 3; kk++) {
                bf16x8 tq = *(const bf16x8*)&qkv[(size_t)qr * 2304 + h * 96 + kk * 32 + l4 * 8];
#pragma unroll
                for (int e = 0; e < 8; e++) tq[e] = (__bf16)((float)tq[e] * scale);
                aq[qs][kk] = tq;
            }
        }
        f32x4 o[2][6] = {};
        float mrun[2][4], lrun[2][4];
#pragma unroll
        for (int qs = 0; qs < 2; ++qs)
#pragma unroll
            for (int rg = 0; rg < 4; rg++) { mrun[qs][rg] = -1e30f; lrun[qs][rg] = 0.f; }

        for (int ktr = 0; ktr < ntile; ++ktr, ++s) {
            const int cur = s & 1;
            const int kt = kt_of(s);
            __syncthreads();                 // (A) Kl[cur]/mk[cur] published; Vt reads done
            stageV(kt);                      // completes by (B)
            if (s + 1 < nsteps) stageK(kt_of(s + 1), cur ^ 1);

            // ---- S = Q K^T (j-outer: K fragments shared by both q-sets) ----
            f32x4 sc[2][4];
#pragma unroll
            for (int j = 0; j < 4; j++) {
                const int rbase = (j * 16 + l15) << 7;
                const int key = l15 & 7;
                bf16x8 bk[3];
#pragma unroll
                for (int kk = 0; kk < 3; kk++)
                    bk[kk] = *(const bf16x8*)&Kl[cur][rbase + (((kk * 4 + l4) ^ key) << 3)];
#pragma unroll
                for (int qs = 0; qs < 2; ++qs) {
                    f32x4 cj = {0.f, 0.f, 0.f, 0.f};
#pragma unroll
                    for (int kk = 0; kk < 3; kk++) cj = mfma16(aq[qs][kk], bk[kk], cj);
                    sc[qs][j] = cj;
                }
            }

#pragma unroll
            for (int qs = 0; qs < 2; ++qs) {
                float tmax[4] = {-1e30f, -1e30f, -1e30f, -1e30f};
#pragma unroll
                for (int j = 0; j < 4; j++) {
                    float mb = mk[cur][j * 16 + l15];
#pragma unroll
                    for (int rg = 0; rg < 4; rg++) {
                        float v = sc[qs][j][rg] + mb;
                        sc[qs][j][rg] = v;
                        tmax[rg] = fmaxf(tmax[rg], v);
                    }
                }
#pragma unroll
                for (int d = 1; d < 16; d <<= 1)
#pragma unroll
                    for (int rg = 0; rg < 4; rg++)
                        tmax[rg] = fmaxf(tmax[rg], __shfl_xor(tmax[rg], d));
                int need = 0;
#pragma unroll
                for (int rg = 0; rg < 4; rg++) need |= (tmax[rg] > mrun[qs][rg] + 8.f) ? 1 : 0;
                if (__any(need)) {
#pragma unroll
                    for (int rg = 0; rg < 4; rg++) {
                        float mn = fmaxf(mrun[qs][rg], tmax[rg]);
                        float corr = __expf(mrun[qs][rg] - mn);
                        mrun[qs][rg] = mn;
                        lrun[qs][rg] *= corr;
#pragma unroll
                        for (int j6 = 0; j6 < 6; j6++) o[qs][j6][rg] *= corr;
                    }
                }
                float tsum[4] = {0.f, 0.f, 0.f, 0.f};
#pragma unroll
                for (int j = 0; j < 4; j++)
#pragma unroll
                    for (int rg = 0; rg < 4; rg++) {
                        float p = __expf(sc[qs][j][rg] - mrun[qs][rg]);
                        tsum[rg] += p;
                        const int prow = l4 * 4 + rg;
                        Pl[qs][wid][(prow << 6) + ((j * 16 + l15) ^ ((prow & 7) << 3))] = f2bf(p);
                    }
#pragma unroll
                for (int d = 1; d < 16; d <<= 1)
#pragma unroll
                    for (int rg = 0; rg < 4; rg++) tsum[rg] += __shfl_xor(tsum[rg], d);
#pragma unroll
                for (int rg = 0; rg < 4; rg++) lrun[qs][rg] += tsum[rg];
            }

            __syncthreads();                 // (B) Vt ready; Kl[cur^1] landed

            // ---- O += P V (j6-outer: V fragments shared by both q-sets) ----
            bf16x8 ap[2][2];
#pragma unroll
            for (int qs = 0; qs < 2; ++qs)
#pragma unroll
                for (int kk = 0; kk < 2; kk++)
                    ap[qs][kk] = *(const bf16x8*)&Pl[qs][wid][(l15 << 6) + (((kk * 4 + l4) ^ (l15 & 7)) << 3)];
#pragma unroll
            for (int j6 = 0; j6 < 6; j6++) {
                const int dbase = (j6 * 16 + l15) << 6;
                const int key = l15 & 7;
                bf16x8 bv[2];
#pragma unroll
                for (int kk = 0; kk < 2; kk++)
                    bv[kk] = *(const bf16x8*)&Vt[dbase + (((kk * 4 + l4) ^ key) << 3)];
#pragma unroll
                for (int qs = 0; qs < 2; ++qs)
#pragma unroll
                    for (int kk = 0; kk < 2; kk++)
                        o[qs][j6] = mfma16(ap[qs][kk], bv[kk], o[qs][j6]);
            }
        }

#pragma unroll
        for (int qs = 0; qs < 2; ++qs) {
            float inv[4];
#pragma unroll
            for (int rg = 0; rg < 4; rg++) inv[rg] = 1.f / lrun[qs][rg];
            const size_t orow = (size_t)(qbaseP + (wid << 5) + qs * 16);
#pragma unroll
            for (int j6 = 0; j6 < 6; j6++)
#pragma unroll
                for (int rg = 0; rg < 4; rg++)
                    attn[(orow + l4 * 4 + rg) * 768 + h * 96 + j6 * 16 + l15] =
                        f2bf(o[qs][j6][rg] * inv[rg]);
        }
    }
}

// ---------- LN1 + masked-pool accumulation ----------
__global__ __launch_bounds__(256) void k_ln_pool(const float* __restrict__ X,
                                                 const int* __restrict__ vmaskc,
                                                 const int* __restrict__ tmaskc,
                                                 const float* __restrict__ g,
                                                 const float* __restrict__ bb,
                                                 float* __restrict__ pooled,
                                                 int mvisL, int bg0) {
    __shared__ float pool[768];
    const int tid = threadIdx.x, wid = tid >> 6, lane = tid & 63;
    const int row0 = blockIdx.x << 5;
    const bool vis = row0 < mvisL;
    const int* mask = vis ? vmaskc : tmaskc;
    const int mbase = vis ? 0 : mvisL;
    const int bl = vis ? (row0 >> 10) : ((row0 - mvisL) >> 9);
    float* pout = pooled + (vis ? 0 : 12288) + (size_t)(bg0 + bl) * 768;

    float gv[12], bv2[12];
#pragma unroll
    for (int k = 0; k < 12; k++) { gv[k] = g[lane + k * 64]; bv2[k] = bb[lane + k * 64]; }
    float acc[12] = {};
    for (int rr = 0; rr < 8; ++rr) {
        const int row = row0 + (wid << 3) + rr;
        const float* x = X + (size_t)row * 768;
        float xs[12], sm = 0.f, s2 = 0.f;
#pragma unroll
        for (int k = 0; k < 12; k++) {
            float tv = x[lane + k * 64];
            xs[k] = tv; sm += tv; s2 += tv * tv;
        }
#pragma unroll
        for (int d = 1; d < 64; d <<= 1) { sm += __shfl_xor(sm, d); s2 += __shfl_xor(s2, d); }
        const float mean = sm * (1.f / 768.f);
        const float rstd = rsqrtf(s2 * (1.f / 768.f) - mean * mean + 1e-5f);
        const float mv = (float)mask[row - mbase];
#pragma unroll
        for (int k = 0; k < 12; k++) acc[k] += ((xs[k] - mean) * rstd * gv[k] + bv2[k]) * mv;
    }
    pool[tid] = 0.f; pool[tid + 256] = 0.f; pool[tid + 512] = 0.f;
    __syncthreads();
#pragma unroll
    for (int k = 0; k < 12; k++) atomicAdd(&pool[lane + k * 64], acc[k]);
    __syncthreads();
    atomicAdd(&pout[tid], pool[tid]);
    atomicAdd(&pout[tid + 256], pool[tid + 256]);
    atomicAdd(&pout[tid + 512], pool[tid + 512]);
}

// ---------- final ----------
__device__ __forceinline__ float blk_sum(float v, volatile float* tmp) {
#pragma unroll
    for (int d = 1; d < 64; d <<= 1) v += __shfl_xor(v, d);
    __syncthreads();
    if ((threadIdx.x & 63) == 0) tmp[threadIdx.x >> 6] = v;
    __syncthreads();
    return tmp[0] + tmp[1] + tmp[2] + tmp[3];
}

__global__ __launch_bounds__(256) void k_final(const float* __restrict__ pooled,
                                               const int* __restrict__ vmask,
                                               const int* __restrict__ tmask,
                                               const float* __restrict__ Wf,
                                               const float* __restrict__ bfv,
                                               const float* __restrict__ g2,
                                               const float* __restrict__ b2,
                                               float* __restrict__ out) {
    __shared__ float sh[1536];
    __shared__ float red[4];
    const int b = blockIdx.x, tid = threadIdx.x;
    float cv = 0.f, ct = 0.f;
    for (int i = tid; i < 1024; i += 256) cv += (float)vmask[(b << 10) + i];
    for (int i = tid; i < 512; i += 256) ct += (float)tmask[(b << 9) + i];
    cv = blk_sum(cv, red);
    ct = blk_sum(ct, red);
    const float iv = 1.f / cv, itv = 1.f / ct;
#pragma unroll
    for (int k = 0; k < 3; k++) {
        int j = tid + (k << 8);
        sh[j] = pooled[b * 768 + j] * iv;
        sh[768 + j] = pooled[12288 + b * 768 + j] * itv;
    }
    __syncthreads();
    float f0 = bfv[tid], f1 = bfv[tid + 256], f2 = bfv[tid + 512];
    for (int i = 0; i < 1536; i++) {
        const float pv = sh[i];
        const float* w = Wf + (size_t)i * 768;
        f0 += pv * w[tid];
        f1 += pv * w[tid + 256];
        f2 += pv * w[tid + 512];
    }
    float sm = blk_sum(f0 + f1 + f2, red);
    float s2 = blk_sum(f0 * f0 + f1 * f1 + f2 * f2, red);
    const float mean = sm * (1.f / 768.f);
    const float rstd = rsqrtf(s2 * (1.f / 768.f) - mean * mean + 1e-5f);
    out[b * 768 + tid] = (f0 - mean) * rstd * g2[tid] + b2[tid];
    out[b * 768 + tid + 256] = (f1 - mean) * rstd * g2[tid + 256] + b2[tid + 256];
    out[b * 768 + tid + 512] = (f2 - mean) * rstd * g2[tid + 512] + b2[tid + 512];
}

// ---------- host ----------
extern "C" void kernel_launch(void* const* d_in, const int* in_sizes, int n_in,
                              void* d_out, int out_size, void* d_ws, size_t ws_size,
                              hipStream_t stream) {
    (void)in_sizes; (void)n_in; (void)out_size;
    const float* vf = (const float*)d_in[0];
    const float* tf = (const float*)d_in[1];
    const int* vmask = (const int*)d_in[2];
    const int* tmask = (const int*)d_in[3];
    const float* Wq = (const float*)d_in[4];
    const float* bq = (const float*)d_in[5];
    const float* Wk = (const float*)d_in[6];
    const float* bk = (const float*)d_in[7];
    const float* Wv = (const float*)d_in[8];
    const float* bv = (const float*)d_in[9];
    const float* Wo = (const float*)d_in[10];
    const float* bo = (const float*)d_in[11];
    const float* g1 = (const float*)d_in[12];
    const float* b1 = (const float*)d_in[13];
    const float* Wf = (const float*)d_in[14];
    const float* bfv = (const float*)d_in[15];
    const float* g2 = (const float*)d_in[16];
    const float* b2 = (const float*)d_in[17];
    float* outp = (float*)d_out;

    // footprint = 4,826,112 + CH * (2,359,296 X + 7,077,888 QKV + 2,359,296 VtG)
    int CH = 16;
    while (CH > 1 && 4826112ull + (size_t)CH * 11796480ull > ws_size) CH >>= 1;
    const int NC = 16 / CH;
    const int Rtot = CH * 1536;

    char* ws = (char*)d_ws;
    u16*   wsW      = (u16*)(ws);
    u16*   wsWo     = (u16*)(ws + 3538944);
    float* wsBqkv   = (float*)(ws + 4718592);
    float* wsPooled = (float*)(ws + 4727808);
    u16*   wsX      = (u16*)(ws + 4826112);                 // [R][768] bf16 (reused: attn out)
    char*  qkvBase  = ws + 4826112 + (size_t)CH * 2359296;
    u16*   wsQKV    = (u16*)qkvBase;                         // [R][2304] bf16 (reused: Oproj f32)
    float* wsOproj  = (float*)qkvBase;
    u16*   wsVtG    = (u16*)(qkvBase + (size_t)CH * 7077888);// [768][R] bf16
    u16*   wsAttn   = wsX;

    k_transpose<<<dim3(144), dim3(256), 0, stream>>>(Wq, wsW, 768, 768);
    k_transpose<<<dim3(144), dim3(256), 0, stream>>>(Wk, wsW + 589824, 768, 768);
    k_transpose<<<dim3(144), dim3(256), 0, stream>>>(Wv, wsW + 1179648, 768, 768);
    k_transpose<<<dim3(144), dim3(256), 0, stream>>>(Wo, wsWo, 768, 768);
    k_bias<<<dim3(9), dim3(256), 0, stream>>>(bq, bk, bv, wsBqkv);
    k_zero<<<dim3(96), dim3(256), 0, stream>>>(wsPooled);

    for (int c = 0; c < NC; ++c) {
        const float* vfc = vf + (size_t)c * CH * 1024 * 768;
        const float* tfc = tf + (size_t)c * CH * 512 * 768;
        const int* vmc = vmask + c * CH * 1024;
        const int* tmc = tmask + c * CH * 512;

        k_cvt_x<<<dim3(CH * 1152), dim3(256), 0, stream>>>(vfc, tfc, wsX, CH * 196608);

        k_gemm<true, false><<<dim3(CH * 216), dim3(256), 0, stream>>>(
            wsX, wsW, wsBqkv, nullptr, nullptr, (void*)wsQKV, 2304, 768, 0);

        k_vtrans<<<dim3(CH * 288), dim3(256), 0, stream>>>(wsQKV, wsVtG, Rtot);

        k_attn<<<dim3(CH * 32), dim3(512), 0, stream>>>(
            wsQKV, wsVtG, vmc, tmc, wsAttn, CH, Rtot);

        k_gemm<false, true><<<dim3(CH * 72), dim3(256), 0, stream>>>(
            wsAttn, wsWo, bo, vfc, tfc, (void*)wsOproj, 768, 768, CH * 1024);

        k_ln_pool<<<dim3(CH * 48), dim3(256), 0, stream>>>(
            wsOproj, vmc, tmc, g1, b1, wsPooled, CH * 1024, c * CH);
    }

    k_final<<<dim3(16), dim3(256), 0, stream>>>(wsPooled, vmask, tmask, Wf, bfv, g2, b2, outp);
}

// Round 10
// 528.217 us; speedup vs baseline: 1.3385x; 1.3385x over previous
//
#include <hip/hip_runtime.h>

typedef __bf16 bf16x8 __attribute__((ext_vector_type(8)));
typedef float f32x4 __attribute__((ext_vector_type(4)));
typedef unsigned short u16;
typedef unsigned int u32;
typedef u16 u16x8 __attribute__((ext_vector_type(8)));
typedef u16 u16x4 __attribute__((ext_vector_type(4)));

// B=16, SV=1024, ST=512, D=768, H=8, DH=96. Chunked over CH batches,
// R = CH*1536 rows (CH*1024 visual then CH*512 text).

__device__ __forceinline__ u16 f2bf(float f) {
    u32 u = __builtin_bit_cast(u32, f);
    u32 r = u + 0x7FFFu + ((u >> 16) & 1u);
    return (u16)(r >> 16);
}

__device__ __forceinline__ f32x4 mfma16(bf16x8 a, bf16x8 b, f32x4 c) {
    return __builtin_amdgcn_mfma_f32_16x16x32_bf16(a, b, c, 0, 0, 0);
}

#define GLOAD_LDS16(g, l) __builtin_amdgcn_global_load_lds( \
    (__attribute__((address_space(1))) void*)(g), \
    (__attribute__((address_space(3))) void*)(l), 16, 0, 0)

// ---------- prep kernels ----------

__global__ __launch_bounds__(256) void k_cvt_x(const float* __restrict__ vf,
                                               const float* __restrict__ tf,
                                               u16* __restrict__ X, int nvis4) {
    int i = blockIdx.x * 256 + threadIdx.x;
    f32x4 v = (i < nvis4) ? ((const f32x4*)vf)[i] : ((const f32x4*)tf)[i - nvis4];
    u16x4 o = { f2bf(v[0]), f2bf(v[1]), f2bf(v[2]), f2bf(v[3]) };
    ((u16x4*)X)[i] = o;
}

// src f32 [K0][N0] -> dst bf16 [N0][K0]   (64x64 LDS tiles)
__global__ __launch_bounds__(256) void k_transpose(const float* __restrict__ src,
                                                   u16* __restrict__ dst,
                                                   int K0, int N0) {
    __shared__ float t[64][65];
    int ntx = N0 >> 6;
    int k0 = (blockIdx.x / ntx) << 6, n0 = (blockIdx.x % ntx) << 6;
    int c = threadIdx.x & 63, rr = threadIdx.x >> 6;
#pragma unroll
    for (int q = 0; q < 16; q++) {
        int r = q * 4 + rr;
        t[r][c] = src[(size_t)(k0 + r) * N0 + n0 + c];
    }
    __syncthreads();
#pragma unroll
    for (int q = 0; q < 16; q++) {
        int r = q * 4 + rr;
        dst[(size_t)(n0 + r) * K0 + k0 + c] = f2bf(t[c][r]);
    }
}

__global__ __launch_bounds__(256) void k_bias(const float* __restrict__ bq,
                                              const float* __restrict__ bk,
                                              const float* __restrict__ bv,
                                              float* __restrict__ bqkv) {
    int n = blockIdx.x * 256 + threadIdx.x;
    if (n < 2304) {
        const float* s = (n < 768) ? bq : ((n < 1536) ? bk : bv);
        int r = (n < 768) ? n : ((n < 1536) ? n - 768 : n - 1536);
        bqkv[n] = s[r];
    }
}

__global__ __launch_bounds__(256) void k_zero(float* __restrict__ p) {
    p[blockIdx.x * 256 + threadIdx.x] = 0.f;
}

// ---------- V global transpose: QKV V-cols [R][768] -> VtG [768][R] bf16 ----------
__global__ __launch_bounds__(256) void k_vtrans(const u16* __restrict__ qkv,
                                                u16* __restrict__ VtG, int Rtot) {
    __shared__ alignas(16) u16 t[64][72];
    const int kt = blockIdx.x / 12, dt = blockIdx.x % 12;
    const int k0 = kt << 6, d0 = dt << 6;
    const int tid = threadIdx.x;
#pragma unroll
    for (int it = 0; it < 2; it++) {
        int c = it * 256 + tid;
        int r = c >> 3, cc = c & 7;
        u16x8 v = *(const u16x8*)&qkv[(size_t)(k0 + r) * 2304 + 1536 + d0 + cc * 8];
        *(u16x8*)&t[r][cc * 8] = v;
    }
    __syncthreads();
#pragma unroll
    for (int it = 0; it < 2; it++) {
        int c = it * 256 + tid;
        int k8 = c & 7, d = c >> 3;
        u16x8 o;
#pragma unroll
        for (int e = 0; e < 8; e++) o[e] = t[k8 * 8 + e][d];
        *(u16x8*)&VtG[(size_t)(d0 + d) * Rtot + k0 + k8 * 8] = o;
    }
}

// ---------- GEMM: C[R][N] = A[R][K] * Bt[N][K]^T + bias (+residual) ----------
// XCD-chunked blockIdx swizzle (grid always a multiple of 8).
template <bool OUT_BF16, bool ADD_RES>
__global__ __launch_bounds__(256) void k_gemm(const u16* __restrict__ A,
                                              const u16* __restrict__ Bt,
                                              const float* __restrict__ bias,
                                              const float* __restrict__ resA,
                                              const float* __restrict__ resB,
                                              void* __restrict__ Cout,
                                              int Ndim, int Kdim, int mvisL) {
    __shared__ alignas(16) u16 sA[128 * 32];
    __shared__ alignas(16) u16 sB[128 * 32];
    const int tid = threadIdx.x, wid = tid >> 6, lane = tid & 63;
    const int nwg = gridDim.x;
    const int wg = (blockIdx.x & 7) * (nwg >> 3) + (blockIdx.x >> 3);
    const int ntiles = Ndim >> 7;
    const int mt = wg / ntiles, nt = wg - mt * ntiles;
    const int m0 = mt << 7, n0 = nt << 7;
    const int wm = wid >> 1, wn = wid & 1;
    f32x4 acc[4][4] = {};

    const int r0 = tid >> 2, p0 = tid & 3;
    const int r1 = 64 + (tid >> 2);
    const u16* ga0 = A + (size_t)(m0 + r0) * Kdim + p0 * 8;
    const u16* ga1 = A + (size_t)(m0 + r1) * Kdim + p0 * 8;
    const u16* gb0 = Bt + (size_t)(n0 + r0) * Kdim + p0 * 8;
    const u16* gb1 = Bt + (size_t)(n0 + r1) * Kdim + p0 * 8;
    u16* lA0 = sA + (wid * 64) * 8;
    u16* lA1 = sA + (256 + wid * 64) * 8;
    u16* lB0 = sB + (wid * 64) * 8;
    u16* lB1 = sB + (256 + wid * 64) * 8;

    const int arow = (wm << 6) + (lane & 15);
    const int brow = (wn << 6) + (lane & 15);
    const int kg = (lane >> 4) * 8;

    for (int kt = 0; kt < Kdim; kt += 32) {
        GLOAD_LDS16(ga0 + kt, lA0);
        GLOAD_LDS16(ga1 + kt, lA1);
        GLOAD_LDS16(gb0 + kt, lB0);
        GLOAD_LDS16(gb1 + kt, lB1);
        __syncthreads();
        bf16x8 av[4], bw[4];
#pragma unroll
        for (int i = 0; i < 4; i++) av[i] = *(const bf16x8*)&sA[(arow + i * 16) * 32 + kg];
#pragma unroll
        for (int j = 0; j < 4; j++) bw[j] = *(const bf16x8*)&sB[(brow + j * 16) * 32 + kg];
#pragma unroll
        for (int i = 0; i < 4; i++)
#pragma unroll
            for (int j = 0; j < 4; j++) acc[i][j] = mfma16(av[i], bw[j], acc[i][j]);
        __syncthreads();
    }

    const int col0 = n0 + (wn << 6) + (lane & 15);
    const int rowb = m0 + (wm << 6) + ((lane >> 4) << 2);
    float bvals[4];
#pragma unroll
    for (int j = 0; j < 4; j++) bvals[j] = bias[col0 + j * 16];
#pragma unroll
    for (int i = 0; i < 4; i++) {
#pragma unroll
        for (int rg = 0; rg < 4; rg++) {
            const int row = rowb + i * 16 + rg;
            const float* rp = nullptr;
            if constexpr (ADD_RES)
                rp = (row < mvisL) ? resA + (size_t)row * 768
                                   : resB + (size_t)(row - mvisL) * 768;
#pragma unroll
            for (int j = 0; j < 4; j++) {
                const int col = col0 + j * 16;
                float v = acc[i][j][rg] + bvals[j];
                if constexpr (ADD_RES) v += rp[col];
                if constexpr (OUT_BF16)
                    ((u16*)Cout)[(size_t)row * Ndim + col] = f2bf(v);
                else
                    ((float*)Cout)[(size_t)row * Ndim + col] = v;
            }
        }
    }
}

// ---------- fused cross-attention ----------
// R7 structure (proven: one barrier per step, K AND V double-buffered,
// stage(s+1) issued after barrier, Pl time-shared across 2 q-sets) with
// parameter changes only: KVBLK=64, grid split in half-q-ranges -> LDS 74 KB
// -> 2 blocks/CU (16 waves). Serpentine k-order for L2 reuse.
__global__ __launch_bounds__(512) void k_attn(const u16* __restrict__ qkv,
                                              const u16* __restrict__ VtG,
                                              const int* __restrict__ vmaskc,
                                              const int* __restrict__ tmaskc,
                                              u16* __restrict__ attn, int CHn, int Rtot) {
    __shared__ alignas(16) u16 Kl[2][64 * 128];   // 32 KB (dbuf)
    __shared__ alignas(16) u16 Vt[2][96 * 64];    // 24 KB (dbuf)
    __shared__ alignas(16) u16 Pl[8][16 * 64];    // 16 KB (time-shared)
    __shared__ float mk[2][64];

    const int bx = blockIdx.x;
    int b, h, half, qbase, kbase, nqt, ntl;
    const int* mask;
    const int vcap = CHn * 16;
    if (bx < vcap) {   // visual q -> text kv: 2 passes x 256 rows, Sk=512
        b = bx >> 4; h = (bx >> 1) & 7; half = bx & 1;
        qbase = (b << 10) + half * 512;
        kbase = (CHn << 10) + (b << 9);
        mask = tmaskc + (b << 9); nqt = 2; ntl = 3;   // ntile=8 (64-row k-tiles)
    } else {           // text q -> visual kv: 1 pass x 256 rows, Sk=1024
        const int bx2 = bx - vcap;
        b = bx2 >> 4; h = (bx2 >> 1) & 7; half = bx2 & 1;
        qbase = (CHn << 10) + (b << 9) + half * 256;
        kbase = b << 10;
        mask = vmaskc + (b << 10); nqt = 1; ntl = 4;  // ntile=16
    }
    const int ntile = 1 << ntl;
    const int nsteps = nqt << ntl;   // 16 both ways
    const int tid = threadIdx.x, wid = tid >> 6, lane = tid & 63;
    const int l15 = lane & 15, l4 = lane >> 4;
    const float scale = 0.10206207261596577f;  // 1/sqrt(96)

    auto kt_of = [&](int s) {
        const int p = s >> ntl, ktr = s & (ntile - 1);
        return (p & 1) ? (ntile - 1 - ktr) : ktr;    // serpentine
    };
    auto stage = [&](int kt, int pb) {
#pragma unroll
        for (int it = 0; it < 2; ++it) {             // K tile: 1024 16B chunks
            const int c = it * 512 + tid;
            const int r = c >> 4, s8 = c & 15;
            const int k8 = s8 ^ (r & 7);
            const u16* src = qkv + (size_t)(kbase + (kt << 6) + r) * 2304 + 768 + h * 96
                             + (k8 < 12 ? k8 * 8 : 0);
            GLOAD_LDS16(src, &Kl[pb][(size_t)c * 8]);
        }
#pragma unroll
        for (int it = 0; it < 2; ++it) {             // V tile: 768 16B chunks
            const int c = it * 512 + tid;
            if (c < 768) {
                const int d = c >> 3, s8v = c & 7;
                const int k8 = s8v ^ (d & 7);
                const u16* src = VtG + (size_t)(h * 96 + d) * Rtot + kbase + (kt << 6) + k8 * 8;
                GLOAD_LDS16(src, &Vt[pb][(size_t)c * 8]);
            }
        }
        if (tid < 64) mk[pb][tid] = mask[(kt << 6) + tid] ? 0.f : -1e30f;
    };

    stage(kt_of(0), 0);
    int s = 0;
    for (int qt = 0; qt < nqt; ++qt) {
        // wave's rows: qbase + qt*256 + wid*32 + qs*16 + l15
        bf16x8 aq[2][3];
#pragma unroll
        for (int qs = 0; qs < 2; ++qs) {
            const int qr = qbase + (qt << 8) + (wid << 5) + qs * 16 + l15;
#pragma unroll
            for (int kk = 0; kk < 3; kk++) {
                bf16x8 tq = *(const bf16x8*)&qkv[(size_t)qr * 2304 + h * 96 + kk * 32 + l4 * 8];
#pragma unroll
                for (int e = 0; e < 8; e++) tq[e] = (__bf16)((float)tq[e] * scale);
                aq[qs][kk] = tq;
            }
        }
        f32x4 o[2][6] = {};
        float mrun[2][4], lrun[2][4];
#pragma unroll
        for (int qs = 0; qs < 2; ++qs)
#pragma unroll
            for (int rg = 0; rg < 4; rg++) { mrun[qs][rg] = -1e30f; lrun[qs][rg] = 0.f; }

        for (int ktr = 0; ktr < ntile; ++ktr, ++s) {
            const int cur = s & 1;
            __syncthreads();                  // publish stage(cur); reads of cur^1 done
            if (s + 1 < nsteps) stage(kt_of(s + 1), cur ^ 1);

            // ---- S = Q K^T (j-outer: K fragments shared by both q-sets) ----
            f32x4 sc[2][4];
#pragma unroll
            for (int j = 0; j < 4; j++) {
                const int rbase = (j * 16 + l15) << 7;
                const int key = l15 & 7;
                bf16x8 bk[3];
#pragma unroll
                for (int kk = 0; kk < 3; kk++)
                    bk[kk] = *(const bf16x8*)&Kl[cur][rbase + (((kk * 4 + l4) ^ key) << 3)];
#pragma unroll
                for (int qs = 0; qs < 2; ++qs) {
                    f32x4 cj = {0.f, 0.f, 0.f, 0.f};
#pragma unroll
                    for (int kk = 0; kk < 3; kk++) cj = mfma16(aq[qs][kk], bk[kk], cj);
                    sc[qs][j] = cj;
                }
            }

#pragma unroll
            for (int qs = 0; qs < 2; ++qs) {
                // ---- additive mask + row max ----
                float tmax[4] = {-1e30f, -1e30f, -1e30f, -1e30f};
#pragma unroll
                for (int j = 0; j < 4; j++) {
                    float mb = mk[cur][j * 16 + l15];
#pragma unroll
                    for (int rg = 0; rg < 4; rg++) {
                        float v = sc[qs][j][rg] + mb;
                        sc[qs][j][rg] = v;
                        tmax[rg] = fmaxf(tmax[rg], v);
                    }
                }
#pragma unroll
                for (int d = 1; d < 16; d <<= 1)
#pragma unroll
                    for (int rg = 0; rg < 4; rg++)
                        tmax[rg] = fmaxf(tmax[rg], __shfl_xor(tmax[rg], d));
                // ---- defer-max rescale (THR=8) ----
                int need = 0;
#pragma unroll
                for (int rg = 0; rg < 4; rg++) need |= (tmax[rg] > mrun[qs][rg] + 8.f) ? 1 : 0;
                if (__any(need)) {
#pragma unroll
                    for (int rg = 0; rg < 4; rg++) {
                        float mn = fmaxf(mrun[qs][rg], tmax[rg]);
                        float corr = __expf(mrun[qs][rg] - mn);
                        mrun[qs][rg] = mn;
                        lrun[qs][rg] *= corr;
#pragma unroll
                        for (int j6 = 0; j6 < 6; j6++) o[qs][j6][rg] *= corr;
                    }
                }
                // ---- P = exp(S - m) -> Pl (time-shared), row sums ----
                float tsum[4] = {0.f, 0.f, 0.f, 0.f};
#pragma unroll
                for (int j = 0; j < 4; j++)
#pragma unroll
                    for (int rg = 0; rg < 4; rg++) {
                        float p = __expf(sc[qs][j][rg] - mrun[qs][rg]);
                        tsum[rg] += p;
                        const int prow = l4 * 4 + rg;
                        Pl[wid][(prow << 6) + ((j * 16 + l15) ^ ((prow & 7) << 3))] = f2bf(p);
                    }
#pragma unroll
                for (int d = 1; d < 16; d <<= 1)
#pragma unroll
                    for (int rg = 0; rg < 4; rg++) tsum[rg] += __shfl_xor(tsum[rg], d);
#pragma unroll
                for (int rg = 0; rg < 4; rg++) lrun[qs][rg] += tsum[rg];

                // ---- O += P V  (same-wave Pl RAW; Vt[cur] staged 1 step ahead) ----
                bf16x8 ap[2];
#pragma unroll
                for (int kk = 0; kk < 2; kk++)
                    ap[kk] = *(const bf16x8*)&Pl[wid][(l15 << 6) + (((kk * 4 + l4) ^ (l15 & 7)) << 3)];
#pragma unroll
                for (int j6 = 0; j6 < 6; j6++) {
                    const int dbase = (j6 * 16 + l15) << 6;
                    const int key = l15 & 7;
#pragma unroll
                    for (int kk = 0; kk < 2; kk++) {
                        bf16x8 bv = *(const bf16x8*)&Vt[cur][dbase + (((kk * 4 + l4) ^ key) << 3)];
                        o[qs][j6] = mfma16(ap[kk], bv, o[qs][j6]);
                    }
                }
            }
        }

#pragma unroll
        for (int qs = 0; qs < 2; ++qs) {
            float inv[4];
#pragma unroll
            for (int rg = 0; rg < 4; rg++) inv[rg] = 1.f / lrun[qs][rg];
            const size_t orow = (size_t)(qbase + (qt << 8) + (wid << 5) + qs * 16);
#pragma unroll
            for (int j6 = 0; j6 < 6; j6++)
#pragma unroll
                for (int rg = 0; rg < 4; rg++)
                    attn[(orow + l4 * 4 + rg) * 768 + h * 96 + j6 * 16 + l15] =
                        f2bf(o[qs][j6][rg] * inv[rg]);
        }
    }
}

// ---------- LN1 + masked-pool accumulation ----------
__global__ __launch_bounds__(256) void k_ln_pool(const float* __restrict__ X,
                                                 const int* __restrict__ vmaskc,
                                                 const int* __restrict__ tmaskc,
                                                 const float* __restrict__ g,
                                                 const float* __restrict__ bb,
                                                 float* __restrict__ pooled,
                                                 int mvisL, int bg0) {
    __shared__ float pool[768];
    const int tid = threadIdx.x, wid = tid >> 6, lane = tid & 63;
    const int row0 = blockIdx.x << 5;
    const bool vis = row0 < mvisL;
    const int* mask = vis ? vmaskc : tmaskc;
    const int mbase = vis ? 0 : mvisL;
    const int bl = vis ? (row0 >> 10) : ((row0 - mvisL) >> 9);
    float* pout = pooled + (vis ? 0 : 12288) + (size_t)(bg0 + bl) * 768;

    float gv[12], bv2[12];
#pragma unroll
    for (int k = 0; k < 12; k++) { gv[k] = g[lane + k * 64]; bv2[k] = bb[lane + k * 64]; }
    float acc[12] = {};
    for (int rr = 0; rr < 8; ++rr) {
        const int row = row0 + (wid << 3) + rr;
        const float* x = X + (size_t)row * 768;
        float xs[12], sm = 0.f, s2 = 0.f;
#pragma unroll
        for (int k = 0; k < 12; k++) {
            float tv = x[lane + k * 64];
            xs[k] = tv; sm += tv; s2 += tv * tv;
        }
#pragma unroll
        for (int d = 1; d < 64; d <<= 1) { sm += __shfl_xor(sm, d); s2 += __shfl_xor(s2, d); }
        const float mean = sm * (1.f / 768.f);
        const float rstd = rsqrtf(s2 * (1.f / 768.f) - mean * mean + 1e-5f);
        const float mv = (float)mask[row - mbase];
#pragma unroll
        for (int k = 0; k < 12; k++) acc[k] += ((xs[k] - mean) * rstd * gv[k] + bv2[k]) * mv;
    }
    pool[tid] = 0.f; pool[tid + 256] = 0.f; pool[tid + 512] = 0.f;
    __syncthreads();
#pragma unroll
    for (int k = 0; k < 12; k++) atomicAdd(&pool[lane + k * 64], acc[k]);
    __syncthreads();
    atomicAdd(&pout[tid], pool[tid]);
    atomicAdd(&pout[tid + 256], pool[tid + 256]);
    atomicAdd(&pout[tid + 512], pool[tid + 512]);
}

// ---------- final ----------
__device__ __forceinline__ float blk_sum(float v, volatile float* tmp) {
#pragma unroll
    for (int d = 1; d < 64; d <<= 1) v += __shfl_xor(v, d);
    __syncthreads();
    if ((threadIdx.x & 63) == 0) tmp[threadIdx.x >> 6] = v;
    __syncthreads();
    return tmp[0] + tmp[1] + tmp[2] + tmp[3];
}

__global__ __launch_bounds__(256) void k_final(const float* __restrict__ pooled,
                                               const int* __restrict__ vmask,
                                               const int* __restrict__ tmask,
                                               const float* __restrict__ Wf,
                                               const float* __restrict__ bfv,
                                               const float* __restrict__ g2,
                                               const float* __restrict__ b2,
                                               float* __restrict__ out) {
    __shared__ float sh[1536];
    __shared__ float red[4];
    const int b = blockIdx.x, tid = threadIdx.x;
    float cv = 0.f, ct = 0.f;
    for (int i = tid; i < 1024; i += 256) cv += (float)vmask[(b << 10) + i];
    for (int i = tid; i < 512; i += 256) ct += (float)tmask[(b << 9) + i];
    cv = blk_sum(cv, red);
    ct = blk_sum(ct, red);
    const float iv = 1.f / cv, itv = 1.f / ct;
#pragma unroll
    for (int k = 0; k < 3; k++) {
        int j = tid + (k << 8);
        sh[j] = pooled[b * 768 + j] * iv;
        sh[768 + j] = pooled[12288 + b * 768 + j] * itv;
    }
    __syncthreads();
    float f0 = bfv[tid], f1 = bfv[tid + 256], f2 = bfv[tid + 512];
    for (int i = 0; i < 1536; i++) {
        const float pv = sh[i];
        const float* w = Wf + (size_t)i * 768;
        f0 += pv * w[tid];
        f1 += pv * w[tid + 256];
        f2 += pv * w[tid + 512];
    }
    float sm = blk_sum(f0 + f1 + f2, red);
    float s2 = blk_sum(f0 * f0 + f1 * f1 + f2 * f2, red);
    const float mean = sm * (1.f / 768.f);
    const float rstd = rsqrtf(s2 * (1.f / 768.f) - mean * mean + 1e-5f);
    out[b * 768 + tid] = (f0 - mean) * rstd * g2[tid] + b2[tid];
    out[b * 768 + tid + 256] = (f1 - mean) * rstd * g2[tid + 256] + b2[tid + 256];
    out[b * 768 + tid + 512] = (f2 - mean) * rstd * g2[tid + 512] + b2[tid + 512];
}

// ---------- host ----------
extern "C" void kernel_launch(void* const* d_in, const int* in_sizes, int n_in,
                              void* d_out, int out_size, void* d_ws, size_t ws_size,
                              hipStream_t stream) {
    (void)in_sizes; (void)n_in; (void)out_size;
    const float* vf = (const float*)d_in[0];
    const float* tf = (const float*)d_in[1];
    const int* vmask = (const int*)d_in[2];
    const int* tmask = (const int*)d_in[3];
    const float* Wq = (const float*)d_in[4];
    const float* bq = (const float*)d_in[5];
    const float* Wk = (const float*)d_in[6];
    const float* bk = (const float*)d_in[7];
    const float* Wv = (const float*)d_in[8];
    const float* bv = (const float*)d_in[9];
    const float* Wo = (const float*)d_in[10];
    const float* bo = (const float*)d_in[11];
    const float* g1 = (const float*)d_in[12];
    const float* b1 = (const float*)d_in[13];
    const float* Wf = (const float*)d_in[14];
    const float* bfv = (const float*)d_in[15];
    const float* g2 = (const float*)d_in[16];
    const float* b2 = (const float*)d_in[17];
    float* outp = (float*)d_out;

    // footprint = 4,826,112 + CH * (2,359,296 X + 7,077,888 QKV + 2,359,296 VtG)
    int CH = 16;
    while (CH > 1 && 4826112ull + (size_t)CH * 11796480ull > ws_size) CH >>= 1;
    const int NC = 16 / CH;
    const int Rtot = CH * 1536;

    char* ws = (char*)d_ws;
    u16*   wsW      = (u16*)(ws);
    u16*   wsWo     = (u16*)(ws + 3538944);
    float* wsBqkv   = (float*)(ws + 4718592);
    float* wsPooled = (float*)(ws + 4727808);
    u16*   wsX      = (u16*)(ws + 4826112);                 // [R][768] bf16 (reused: attn out)
    char*  qkvBase  = ws + 4826112 + (size_t)CH * 2359296;
    u16*   wsQKV    = (u16*)qkvBase;                         // [R][2304] bf16 (reused: Oproj f32)
    float* wsOproj  = (float*)qkvBase;
    u16*   wsVtG    = (u16*)(qkvBase + (size_t)CH * 7077888);// [768][R] bf16
    u16*   wsAttn   = wsX;

    k_transpose<<<dim3(144), dim3(256), 0, stream>>>(Wq, wsW, 768, 768);
    k_transpose<<<dim3(144), dim3(256), 0, stream>>>(Wk, wsW + 589824, 768, 768);
    k_transpose<<<dim3(144), dim3(256), 0, stream>>>(Wv, wsW + 1179648, 768, 768);
    k_transpose<<<dim3(144), dim3(256), 0, stream>>>(Wo, wsWo, 768, 768);
    k_bias<<<dim3(9), dim3(256), 0, stream>>>(bq, bk, bv, wsBqkv);
    k_zero<<<dim3(96), dim3(256), 0, stream>>>(wsPooled);

    for (int c = 0; c < NC; ++c) {
        const float* vfc = vf + (size_t)c * CH * 1024 * 768;
        const float* tfc = tf + (size_t)c * CH * 512 * 768;
        const int* vmc = vmask + c * CH * 1024;
        const int* tmc = tmask + c * CH * 512;

        k_cvt_x<<<dim3(CH * 1152), dim3(256), 0, stream>>>(vfc, tfc, wsX, CH * 196608);

        k_gemm<true, false><<<dim3(CH * 216), dim3(256), 0, stream>>>(
            wsX, wsW, wsBqkv, nullptr, nullptr, (void*)wsQKV, 2304, 768, 0);

        k_vtrans<<<dim3(CH * 288), dim3(256), 0, stream>>>(wsQKV, wsVtG, Rtot);

        k_attn<<<dim3(CH * 32), dim3(512), 0, stream>>>(
            wsQKV, wsVtG, vmc, tmc, wsAttn, CH, Rtot);

        k_gemm<false, true><<<dim3(CH * 72), dim3(256), 0, stream>>>(
            wsAttn, wsWo, bo, vfc, tfc, (void*)wsOproj, 768, 768, CH * 1024);

        k_ln_pool<<<dim3(CH * 48), dim3(256), 0, stream>>>(
            wsOproj, vmc, tmc, g1, b1, wsPooled, CH * 1024, c * CH);
    }

    k_final<<<dim3(16), dim3(256), 0, stream>>>(wsPooled, vmask, tmask, Wf, bfv, g2, b2, outp);
}

// Round 11
// 524.627 us; speedup vs baseline: 1.3476x; 1.0068x over previous
//
#include <hip/hip_runtime.h>

typedef __bf16 bf16x8 __attribute__((ext_vector_type(8)));
typedef float f32x4 __attribute__((ext_vector_type(4)));
typedef unsigned short u16;
typedef unsigned int u32;
typedef u16 u16x8 __attribute__((ext_vector_type(8)));
typedef u16 u16x4 __attribute__((ext_vector_type(4)));

// B=16, SV=1024, ST=512, D=768, H=8, DH=96. Chunked over CH batches,
// R = CH*1536 rows (CH*1024 visual then CH*512 text).

__device__ __forceinline__ u16 f2bf(float f) {
    u32 u = __builtin_bit_cast(u32, f);
    u32 r = u + 0x7FFFu + ((u >> 16) & 1u);
    return (u16)(r >> 16);
}

__device__ __forceinline__ f32x4 mfma16(bf16x8 a, bf16x8 b, f32x4 c) {
    return __builtin_amdgcn_mfma_f32_16x16x32_bf16(a, b, c, 0, 0, 0);
}

#define GLOAD_LDS16(g, l) __builtin_amdgcn_global_load_lds( \
    (__attribute__((address_space(1))) void*)(g), \
    (__attribute__((address_space(3))) void*)(l), 16, 0, 0)

// ---------- prep kernels ----------

__global__ __launch_bounds__(256) void k_cvt_x(const float* __restrict__ vf,
                                               const float* __restrict__ tf,
                                               u16* __restrict__ X, int nvis4) {
    int i = blockIdx.x * 256 + threadIdx.x;
    f32x4 v = (i < nvis4) ? ((const f32x4*)vf)[i] : ((const f32x4*)tf)[i - nvis4];
    u16x4 o = { f2bf(v[0]), f2bf(v[1]), f2bf(v[2]), f2bf(v[3]) };
    ((u16x4*)X)[i] = o;
}

// src f32 [K0][N0] -> dst bf16 [N0][K0]   (64x64 LDS tiles)
__global__ __launch_bounds__(256) void k_transpose(const float* __restrict__ src,
                                                   u16* __restrict__ dst,
                                                   int K0, int N0) {
    __shared__ float t[64][65];
    int ntx = N0 >> 6;
    int k0 = (blockIdx.x / ntx) << 6, n0 = (blockIdx.x % ntx) << 6;
    int c = threadIdx.x & 63, rr = threadIdx.x >> 6;
#pragma unroll
    for (int q = 0; q < 16; q++) {
        int r = q * 4 + rr;
        t[r][c] = src[(size_t)(k0 + r) * N0 + n0 + c];
    }
    __syncthreads();
#pragma unroll
    for (int q = 0; q < 16; q++) {
        int r = q * 4 + rr;
        dst[(size_t)(n0 + r) * K0 + k0 + c] = f2bf(t[c][r]);
    }
}

__global__ __launch_bounds__(256) void k_bias(const float* __restrict__ bq,
                                              const float* __restrict__ bk,
                                              const float* __restrict__ bv,
                                              float* __restrict__ bqkv) {
    int n = blockIdx.x * 256 + threadIdx.x;
    if (n < 2304) {
        const float* s = (n < 768) ? bq : ((n < 1536) ? bk : bv);
        int r = (n < 768) ? n : ((n < 1536) ? n - 768 : n - 1536);
        bqkv[n] = s[r];
    }
}

__global__ __launch_bounds__(256) void k_zero(float* __restrict__ p) {
    p[blockIdx.x * 256 + threadIdx.x] = 0.f;
}

// ---------- V global transpose: QKV V-cols [R][768] -> VtG [768][R] bf16 ----------
__global__ __launch_bounds__(256) void k_vtrans(const u16* __restrict__ qkv,
                                                u16* __restrict__ VtG, int Rtot) {
    __shared__ alignas(16) u16 t[64][72];
    const int kt = blockIdx.x / 12, dt = blockIdx.x % 12;
    const int k0 = kt << 6, d0 = dt << 6;
    const int tid = threadIdx.x;
#pragma unroll
    for (int it = 0; it < 2; it++) {
        int c = it * 256 + tid;
        int r = c >> 3, cc = c & 7;
        u16x8 v = *(const u16x8*)&qkv[(size_t)(k0 + r) * 2304 + 1536 + d0 + cc * 8];
        *(u16x8*)&t[r][cc * 8] = v;
    }
    __syncthreads();
#pragma unroll
    for (int it = 0; it < 2; it++) {
        int c = it * 256 + tid;
        int k8 = c & 7, d = c >> 3;
        u16x8 o;
#pragma unroll
        for (int e = 0; e < 8; e++) o[e] = t[k8 * 8 + e][d];
        *(u16x8*)&VtG[(size_t)(d0 + d) * Rtot + k0 + k8 * 8] = o;
    }
}

// ---------- GEMM: C[R][N] = A[R][K] * Bt[N][K]^T + bias (+residual) ----------
// XCD-chunked blockIdx swizzle (grid always a multiple of 8).
template <bool OUT_BF16, bool ADD_RES>
__global__ __launch_bounds__(256) void k_gemm(const u16* __restrict__ A,
                                              const u16* __restrict__ Bt,
                                              const float* __restrict__ bias,
                                              const float* __restrict__ resA,
                                              const float* __restrict__ resB,
                                              void* __restrict__ Cout,
                                              int Ndim, int Kdim, int mvisL) {
    __shared__ alignas(16) u16 sA[128 * 32];
    __shared__ alignas(16) u16 sB[128 * 32];
    const int tid = threadIdx.x, wid = tid >> 6, lane = tid & 63;
    const int nwg = gridDim.x;
    const int wg = (blockIdx.x & 7) * (nwg >> 3) + (blockIdx.x >> 3);
    const int ntiles = Ndim >> 7;
    const int mt = wg / ntiles, nt = wg - mt * ntiles;
    const int m0 = mt << 7, n0 = nt << 7;
    const int wm = wid >> 1, wn = wid & 1;
    f32x4 acc[4][4] = {};

    const int r0 = tid >> 2, p0 = tid & 3;
    const int r1 = 64 + (tid >> 2);
    const u16* ga0 = A + (size_t)(m0 + r0) * Kdim + p0 * 8;
    const u16* ga1 = A + (size_t)(m0 + r1) * Kdim + p0 * 8;
    const u16* gb0 = Bt + (size_t)(n0 + r0) * Kdim + p0 * 8;
    const u16* gb1 = Bt + (size_t)(n0 + r1) * Kdim + p0 * 8;
    u16* lA0 = sA + (wid * 64) * 8;
    u16* lA1 = sA + (256 + wid * 64) * 8;
    u16* lB0 = sB + (wid * 64) * 8;
    u16* lB1 = sB + (256 + wid * 64) * 8;

    const int arow = (wm << 6) + (lane & 15);
    const int brow = (wn << 6) + (lane & 15);
    const int kg = (lane >> 4) * 8;

    for (int kt = 0; kt < Kdim; kt += 32) {
        GLOAD_LDS16(ga0 + kt, lA0);
        GLOAD_LDS16(ga1 + kt, lA1);
        GLOAD_LDS16(gb0 + kt, lB0);
        GLOAD_LDS16(gb1 + kt, lB1);
        __syncthreads();
        bf16x8 av[4], bw[4];
#pragma unroll
        for (int i = 0; i < 4; i++) av[i] = *(const bf16x8*)&sA[(arow + i * 16) * 32 + kg];
#pragma unroll
        for (int j = 0; j < 4; j++) bw[j] = *(const bf16x8*)&sB[(brow + j * 16) * 32 + kg];
#pragma unroll
        for (int i = 0; i < 4; i++)
#pragma unroll
            for (int j = 0; j < 4; j++) acc[i][j] = mfma16(av[i], bw[j], acc[i][j]);
        __syncthreads();
    }

    const int col0 = n0 + (wn << 6) + (lane & 15);
    const int rowb = m0 + (wm << 6) + ((lane >> 4) << 2);
    float bvals[4];
#pragma unroll
    for (int j = 0; j < 4; j++) bvals[j] = bias[col0 + j * 16];
#pragma unroll
    for (int i = 0; i < 4; i++) {
#pragma unroll
        for (int rg = 0; rg < 4; rg++) {
            const int row = rowb + i * 16 + rg;
            const float* rp = nullptr;
            if constexpr (ADD_RES)
                rp = (row < mvisL) ? resA + (size_t)row * 768
                                   : resB + (size_t)(row - mvisL) * 768;
#pragma unroll
            for (int j = 0; j < 4; j++) {
                const int col = col0 + j * 16;
                float v = acc[i][j][rg] + bvals[j];
                if constexpr (ADD_RES) v += rp[col];
                if constexpr (OUT_BF16)
                    ((u16*)Cout)[(size_t)row * Ndim + col] = f2bf(v);
                else
                    ((float*)Cout)[(size_t)row * Ndim + col] = v;
            }
        }
    }
}

// ---------- fused cross-attention ----------
// R10 structure (proven sync: one barrier per step, K AND V double-buffered,
// stage(s+1) issued right after the barrier, serpentine k-order). Parameter
// change only: ONE q-set of 128 rows per pass (halves live registers so
// total VGPR+AGPR fits 4 waves/SIMD -> 2 blocks/CU). LDS 72.5 KB.
__global__ __launch_bounds__(512) void k_attn(const u16* __restrict__ qkv,
                                              const u16* __restrict__ VtG,
                                              const int* __restrict__ vmaskc,
                                              const int* __restrict__ tmaskc,
                                              u16* __restrict__ attn, int CHn, int Rtot) {
    __shared__ alignas(16) u16 Kl[2][64 * 128];   // 32 KB (dbuf)
    __shared__ alignas(16) u16 Vt[2][96 * 64];    // 24 KB (dbuf)
    __shared__ alignas(16) u16 Pl[8][16 * 64];    // 16 KB
    __shared__ float mk[2][64];

    const int bx = blockIdx.x;
    int b, h, half, qbase, kbase, nqt, ntl;
    const int* mask;
    const int vcap = CHn * 16;
    if (bx < vcap) {   // visual q -> text kv: 4 passes x 128 rows, Sk=512
        b = bx >> 4; h = (bx >> 1) & 7; half = bx & 1;
        qbase = (b << 10) + half * 512;
        kbase = (CHn << 10) + (b << 9);
        mask = tmaskc + (b << 9); nqt = 4; ntl = 3;   // ntile=8 (64-row k-tiles)
    } else {           // text q -> visual kv: 2 passes x 128 rows, Sk=1024
        const int bx2 = bx - vcap;
        b = bx2 >> 4; h = (bx2 >> 1) & 7; half = bx2 & 1;
        qbase = (CHn << 10) + (b << 9) + half * 256;
        kbase = b << 10;
        mask = vmaskc + (b << 10); nqt = 2; ntl = 4;  // ntile=16
    }
    const int ntile = 1 << ntl;
    const int nsteps = nqt << ntl;   // 32 both ways
    const int tid = threadIdx.x, wid = tid >> 6, lane = tid & 63;
    const int l15 = lane & 15, l4 = lane >> 4;
    const float scale = 0.10206207261596577f;  // 1/sqrt(96)

    auto kt_of = [&](int s) {
        const int p = s >> ntl, ktr = s & (ntile - 1);
        return (p & 1) ? (ntile - 1 - ktr) : ktr;    // serpentine
    };
    auto stage = [&](int kt, int pb) {
#pragma unroll
        for (int it = 0; it < 2; ++it) {             // K tile: 1024 16B chunks
            const int c = it * 512 + tid;
            const int r = c >> 4, s8 = c & 15;
            const int k8 = s8 ^ (r & 7);
            const u16* src = qkv + (size_t)(kbase + (kt << 6) + r) * 2304 + 768 + h * 96
                             + (k8 < 12 ? k8 * 8 : 0);
            GLOAD_LDS16(src, &Kl[pb][(size_t)c * 8]);
        }
#pragma unroll
        for (int it = 0; it < 2; ++it) {             // V tile: 768 16B chunks
            const int c = it * 512 + tid;
            if (c < 768) {
                const int d = c >> 3, s8v = c & 7;
                const int k8 = s8v ^ (d & 7);
                const u16* src = VtG + (size_t)(h * 96 + d) * Rtot + kbase + (kt << 6) + k8 * 8;
                GLOAD_LDS16(src, &Vt[pb][(size_t)c * 8]);
            }
        }
        if (tid < 64) mk[pb][tid] = mask[(kt << 6) + tid] ? 0.f : -1e30f;
    };

    stage(kt_of(0), 0);
    int s = 0;
    for (int qt = 0; qt < nqt; ++qt) {
        // wave's 16 rows: qbase + qt*128 + wid*16 + l15
        const int qr = qbase + (qt << 7) + (wid << 4) + l15;
        bf16x8 aq[3];
#pragma unroll
        for (int kk = 0; kk < 3; kk++) {
            bf16x8 tq = *(const bf16x8*)&qkv[(size_t)qr * 2304 + h * 96 + kk * 32 + l4 * 8];
#pragma unroll
            for (int e = 0; e < 8; e++) tq[e] = (__bf16)((float)tq[e] * scale);
            aq[kk] = tq;
        }
        f32x4 o[6] = {};
        float mrun[4] = {-1e30f, -1e30f, -1e30f, -1e30f};
        float lrun[4] = {0.f, 0.f, 0.f, 0.f};

        for (int ktr = 0; ktr < ntile; ++ktr, ++s) {
            const int cur = s & 1;
            __syncthreads();                  // publish stage(cur); reads of cur^1 done
            if (s + 1 < nsteps) stage(kt_of(s + 1), cur ^ 1);

            // ---- S = Q K^T ----
            f32x4 sc[4];
#pragma unroll
            for (int j = 0; j < 4; j++) {
                const int rbase = (j * 16 + l15) << 7;
                const int key = l15 & 7;
                f32x4 cj = {0.f, 0.f, 0.f, 0.f};
#pragma unroll
                for (int kk = 0; kk < 3; kk++) {
                    bf16x8 bk = *(const bf16x8*)&Kl[cur][rbase + (((kk * 4 + l4) ^ key) << 3)];
                    cj = mfma16(aq[kk], bk, cj);
                }
                sc[j] = cj;
            }

            // ---- additive mask + row max ----
            float tmax[4] = {-1e30f, -1e30f, -1e30f, -1e30f};
#pragma unroll
            for (int j = 0; j < 4; j++) {
                float mb = mk[cur][j * 16 + l15];
#pragma unroll
                for (int rg = 0; rg < 4; rg++) {
                    float v = sc[j][rg] + mb;
                    sc[j][rg] = v;
                    tmax[rg] = fmaxf(tmax[rg], v);
                }
            }
#pragma unroll
            for (int d = 1; d < 16; d <<= 1)
#pragma unroll
                for (int rg = 0; rg < 4; rg++)
                    tmax[rg] = fmaxf(tmax[rg], __shfl_xor(tmax[rg], d));
            // ---- defer-max rescale (THR=8) ----
            int need = 0;
#pragma unroll
            for (int rg = 0; rg < 4; rg++) need |= (tmax[rg] > mrun[rg] + 8.f) ? 1 : 0;
            if (__any(need)) {
#pragma unroll
                for (int rg = 0; rg < 4; rg++) {
                    float mn = fmaxf(mrun[rg], tmax[rg]);
                    float corr = __expf(mrun[rg] - mn);
                    mrun[rg] = mn;
                    lrun[rg] *= corr;
#pragma unroll
                    for (int j6 = 0; j6 < 6; j6++) o[j6][rg] *= corr;
                }
            }
            // ---- P = exp(S - m) -> Pl, row sums ----
            float tsum[4] = {0.f, 0.f, 0.f, 0.f};
#pragma unroll
            for (int j = 0; j < 4; j++)
#pragma unroll
                for (int rg = 0; rg < 4; rg++) {
                    float p = __expf(sc[j][rg] - mrun[rg]);
                    tsum[rg] += p;
                    const int prow = l4 * 4 + rg;
                    Pl[wid][(prow << 6) + ((j * 16 + l15) ^ ((prow & 7) << 3))] = f2bf(p);
                }
#pragma unroll
            for (int d = 1; d < 16; d <<= 1)
#pragma unroll
                for (int rg = 0; rg < 4; rg++) tsum[rg] += __shfl_xor(tsum[rg], d);
#pragma unroll
            for (int rg = 0; rg < 4; rg++) lrun[rg] += tsum[rg];

            // ---- O += P V  (same-wave Pl RAW; Vt[cur] staged 1 step ahead) ----
            bf16x8 ap[2];
#pragma unroll
            for (int kk = 0; kk < 2; kk++)
                ap[kk] = *(const bf16x8*)&Pl[wid][(l15 << 6) + (((kk * 4 + l4) ^ (l15 & 7)) << 3)];
#pragma unroll
            for (int j6 = 0; j6 < 6; j6++) {
                const int dbase = (j6 * 16 + l15) << 6;
                const int key = l15 & 7;
#pragma unroll
                for (int kk = 0; kk < 2; kk++) {
                    bf16x8 bv = *(const bf16x8*)&Vt[cur][dbase + (((kk * 4 + l4) ^ key) << 3)];
                    o[j6] = mfma16(ap[kk], bv, o[j6]);
                }
            }
        }

        float inv[4];
#pragma unroll
        for (int rg = 0; rg < 4; rg++) inv[rg] = 1.f / lrun[rg];
        const size_t orow = (size_t)(qbase + (qt << 7) + (wid << 4));
#pragma unroll
        for (int j6 = 0; j6 < 6; j6++)
#pragma unroll
            for (int rg = 0; rg < 4; rg++)
                attn[(orow + l4 * 4 + rg) * 768 + h * 96 + j6 * 16 + l15] =
                    f2bf(o[j6][rg] * inv[rg]);
    }
}

// ---------- LN1 + masked-pool accumulation ----------
__global__ __launch_bounds__(256) void k_ln_pool(const float* __restrict__ X,
                                                 const int* __restrict__ vmaskc,
                                                 const int* __restrict__ tmaskc,
                                                 const float* __restrict__ g,
                                                 const float* __restrict__ bb,
                                                 float* __restrict__ pooled,
                                                 int mvisL, int bg0) {
    __shared__ float pool[768];
    const int tid = threadIdx.x, wid = tid >> 6, lane = tid & 63;
    const int row0 = blockIdx.x << 5;
    const bool vis = row0 < mvisL;
    const int* mask = vis ? vmaskc : tmaskc;
    const int mbase = vis ? 0 : mvisL;
    const int bl = vis ? (row0 >> 10) : ((row0 - mvisL) >> 9);
    float* pout = pooled + (vis ? 0 : 12288) + (size_t)(bg0 + bl) * 768;

    float gv[12], bv2[12];
#pragma unroll
    for (int k = 0; k < 12; k++) { gv[k] = g[lane + k * 64]; bv2[k] = bb[lane + k * 64]; }
    float acc[12] = {};
    for (int rr = 0; rr < 8; ++rr) {
        const int row = row0 + (wid << 3) + rr;
        const float* x = X + (size_t)row * 768;
        float xs[12], sm = 0.f, s2 = 0.f;
#pragma unroll
        for (int k = 0; k < 12; k++) {
            float tv = x[lane + k * 64];
            xs[k] = tv; sm += tv; s2 += tv * tv;
        }
#pragma unroll
        for (int d = 1; d < 64; d <<= 1) { sm += __shfl_xor(sm, d); s2 += __shfl_xor(s2, d); }
        const float mean = sm * (1.f / 768.f);
        const float rstd = rsqrtf(s2 * (1.f / 768.f) - mean * mean + 1e-5f);
        const float mv = (float)mask[row - mbase];
#pragma unroll
        for (int k = 0; k < 12; k++) acc[k] += ((xs[k] - mean) * rstd * gv[k] + bv2[k]) * mv;
    }
    pool[tid] = 0.f; pool[tid + 256] = 0.f; pool[tid + 512] = 0.f;
    __syncthreads();
#pragma unroll
    for (int k = 0; k < 12; k++) atomicAdd(&pool[lane + k * 64], acc[k]);
    __syncthreads();
    atomicAdd(&pout[tid], pool[tid]);
    atomicAdd(&pout[tid + 256], pool[tid + 256]);
    atomicAdd(&pout[tid + 512], pool[tid + 512]);
}

// ---------- final ----------
__device__ __forceinline__ float blk_sum(float v, volatile float* tmp) {
#pragma unroll
    for (int d = 1; d < 64; d <<= 1) v += __shfl_xor(v, d);
    __syncthreads();
    if ((threadIdx.x & 63) == 0) tmp[threadIdx.x >> 6] = v;
    __syncthreads();
    return tmp[0] + tmp[1] + tmp[2] + tmp[3];
}

__global__ __launch_bounds__(256) void k_final(const float* __restrict__ pooled,
                                               const int* __restrict__ vmask,
                                               const int* __restrict__ tmask,
                                               const float* __restrict__ Wf,
                                               const float* __restrict__ bfv,
                                               const float* __restrict__ g2,
                                               const float* __restrict__ b2,
                                               float* __restrict__ out) {
    __shared__ float sh[1536];
    __shared__ float red[4];
    const int b = blockIdx.x, tid = threadIdx.x;
    float cv = 0.f, ct = 0.f;
    for (int i = tid; i < 1024; i += 256) cv += (float)vmask[(b << 10) + i];
    for (int i = tid; i < 512; i += 256) ct += (float)tmask[(b << 9) + i];
    cv = blk_sum(cv, red);
    ct = blk_sum(ct, red);
    const float iv = 1.f / cv, itv = 1.f / ct;
#pragma unroll
    for (int k = 0; k < 3; k++) {
        int j = tid + (k << 8);
        sh[j] = pooled[b * 768 + j] * iv;
        sh[768 + j] = pooled[12288 + b * 768 + j] * itv;
    }
    __syncthreads();
    float f0 = bfv[tid], f1 = bfv[tid + 256], f2 = bfv[tid + 512];
    for (int i = 0; i < 1536; i++) {
        const float pv = sh[i];
        const float* w = Wf + (size_t)i * 768;
        f0 += pv * w[tid];
        f1 += pv * w[tid + 256];
        f2 += pv * w[tid + 512];
    }
    float sm = blk_sum(f0 + f1 + f2, red);
    float s2 = blk_sum(f0 * f0 + f1 * f1 + f2 * f2, red);
    const float mean = sm * (1.f / 768.f);
    const float rstd = rsqrtf(s2 * (1.f / 768.f) - mean * mean + 1e-5f);
    out[b * 768 + tid] = (f0 - mean) * rstd * g2[tid] + b2[tid];
    out[b * 768 + tid + 256] = (f1 - mean) * rstd * g2[tid + 256] + b2[tid + 256];
    out[b * 768 + tid + 512] = (f2 - mean) * rstd * g2[tid + 512] + b2[tid + 512];
}

// ---------- host ----------
extern "C" void kernel_launch(void* const* d_in, const int* in_sizes, int n_in,
                              void* d_out, int out_size, void* d_ws, size_t ws_size,
                              hipStream_t stream) {
    (void)in_sizes; (void)n_in; (void)out_size;
    const float* vf = (const float*)d_in[0];
    const float* tf = (const float*)d_in[1];
    const int* vmask = (const int*)d_in[2];
    const int* tmask = (const int*)d_in[3];
    const float* Wq = (const float*)d_in[4];
    const float* bq = (const float*)d_in[5];
    const float* Wk = (const float*)d_in[6];
    const float* bk = (const float*)d_in[7];
    const float* Wv = (const float*)d_in[8];
    const float* bv = (const float*)d_in[9];
    const float* Wo = (const float*)d_in[10];
    const float* bo = (const float*)d_in[11];
    const float* g1 = (const float*)d_in[12];
    const float* b1 = (const float*)d_in[13];
    const float* Wf = (const float*)d_in[14];
    const float* bfv = (const float*)d_in[15];
    const float* g2 = (const float*)d_in[16];
    const float* b2 = (const float*)d_in[17];
    float* outp = (float*)d_out;

    // footprint = 4,826,112 + CH * (2,359,296 X + 7,077,888 QKV + 2,359,296 VtG)
    int CH = 16;
    while (CH > 1 && 4826112ull + (size_t)CH * 11796480ull > ws_size) CH >>= 1;
    const int NC = 16 / CH;
    const int Rtot = CH * 1536;

    char* ws = (char*)d_ws;
    u16*   wsW      = (u16*)(ws);
    u16*   wsWo     = (u16*)(ws + 3538944);
    float* wsBqkv   = (float*)(ws + 4718592);
    float* wsPooled = (float*)(ws + 4727808);
    u16*   wsX      = (u16*)(ws + 4826112);                 // [R][768] bf16 (reused: attn out)
    char*  qkvBase  = ws + 4826112 + (size_t)CH * 2359296;
    u16*   wsQKV    = (u16*)qkvBase;                         // [R][2304] bf16 (reused: Oproj f32)
    float* wsOproj  = (float*)qkvBase;
    u16*   wsVtG    = (u16*)(qkvBase + (size_t)CH * 7077888);// [768][R] bf16
    u16*   wsAttn   = wsX;

    k_transpose<<<dim3(144), dim3(256), 0, stream>>>(Wq, wsW, 768, 768);
    k_transpose<<<dim3(144), dim3(256), 0, stream>>>(Wk, wsW + 589824, 768, 768);
    k_transpose<<<dim3(144), dim3(256), 0, stream>>>(Wv, wsW + 1179648, 768, 768);
    k_transpose<<<dim3(144), dim3(256), 0, stream>>>(Wo, wsWo, 768, 768);
    k_bias<<<dim3(9), dim3(256), 0, stream>>>(bq, bk, bv, wsBqkv);
    k_zero<<<dim3(96), dim3(256), 0, stream>>>(wsPooled);

    for (int c = 0; c < NC; ++c) {
        const float* vfc = vf + (size_t)c * CH * 1024 * 768;
        const float* tfc = tf + (size_t)c * CH * 512 * 768;
        const int* vmc = vmask + c * CH * 1024;
        const int* tmc = tmask + c * CH * 512;

        k_cvt_x<<<dim3(CH * 1152), dim3(256), 0, stream>>>(vfc, tfc, wsX, CH * 196608);

        k_gemm<true, false><<<dim3(CH * 216), dim3(256), 0, stream>>>(
            wsX, wsW, wsBqkv, nullptr, nullptr, (void*)wsQKV, 2304, 768, 0);

        k_vtrans<<<dim3(CH * 288), dim3(256), 0, stream>>>(wsQKV, wsVtG, Rtot);

        k_attn<<<dim3(CH * 32), dim3(512), 0, stream>>>(
            wsQKV, wsVtG, vmc, tmc, wsAttn, CH, Rtot);

        k_gemm<false, true><<<dim3(CH * 72), dim3(256), 0, stream>>>(
            wsAttn, wsWo, bo, vfc, tfc, (void*)wsOproj, 768, 768, CH * 1024);

        k_ln_pool<<<dim3(CH * 48), dim3(256), 0, stream>>>(
            wsOproj, vmc, tmc, g1, b1, wsPooled, CH * 1024, c * CH);
    }

    k_final<<<dim3(16), dim3(256), 0, stream>>>(wsPooled, vmask, tmask, Wf, bfv, g2, b2, outp);
}

// Round 12
// 446.833 us; speedup vs baseline: 1.5823x; 1.1741x over previous
//
#include <hip/hip_runtime.h>

typedef __bf16 bf16x8 __attribute__((ext_vector_type(8)));
typedef float f32x4 __attribute__((ext_vector_type(4)));
typedef unsigned short u16;
typedef unsigned int u32;
typedef u16 u16x8 __attribute__((ext_vector_type(8)));
typedef u16 u16x4 __attribute__((ext_vector_type(4)));

// B=16, SV=1024, ST=512, D=768, H=8, DH=96. Chunked over CH batches,
// R = CH*1536 rows (CH*1024 visual then CH*512 text).

__device__ __forceinline__ u16 f2bf(float f) {
    u32 u = __builtin_bit_cast(u32, f);
    u32 r = u + 0x7FFFu + ((u >> 16) & 1u);
    return (u16)(r >> 16);
}

__device__ __forceinline__ float bf2f(u16 b) {
    u32 u = ((u32)b) << 16;
    return __builtin_bit_cast(float, u);
}

__device__ __forceinline__ f32x4 mfma16(bf16x8 a, bf16x8 b, f32x4 c) {
    return __builtin_amdgcn_mfma_f32_16x16x32_bf16(a, b, c, 0, 0, 0);
}

#define GLOAD_LDS16(g, l) __builtin_amdgcn_global_load_lds( \
    (__attribute__((address_space(1))) void*)(g), \
    (__attribute__((address_space(3))) void*)(l), 16, 0, 0)

// ---------- prep kernels ----------

__global__ __launch_bounds__(256) void k_cvt_x(const float* __restrict__ vf,
                                               const float* __restrict__ tf,
                                               u16* __restrict__ X, int nvis4) {
    int i = blockIdx.x * 256 + threadIdx.x;
    f32x4 v = (i < nvis4) ? ((const f32x4*)vf)[i] : ((const f32x4*)tf)[i - nvis4];
    u16x4 o = { f2bf(v[0]), f2bf(v[1]), f2bf(v[2]), f2bf(v[3]) };
    ((u16x4*)X)[i] = o;
}

// src f32 [K0][N0] -> dst bf16 [N0][K0]   (64x64 LDS tiles)
__global__ __launch_bounds__(256) void k_transpose(const float* __restrict__ src,
                                                   u16* __restrict__ dst,
                                                   int K0, int N0) {
    __shared__ float t[64][65];
    int ntx = N0 >> 6;
    int k0 = (blockIdx.x / ntx) << 6, n0 = (blockIdx.x % ntx) << 6;
    int c = threadIdx.x & 63, rr = threadIdx.x >> 6;
#pragma unroll
    for (int q = 0; q < 16; q++) {
        int r = q * 4 + rr;
        t[r][c] = src[(size_t)(k0 + r) * N0 + n0 + c];
    }
    __syncthreads();
#pragma unroll
    for (int q = 0; q < 16; q++) {
        int r = q * 4 + rr;
        dst[(size_t)(n0 + r) * K0 + k0 + c] = f2bf(t[c][r]);
    }
}

__global__ __launch_bounds__(256) void k_bias(const float* __restrict__ bq,
                                              const float* __restrict__ bk,
                                              const float* __restrict__ bv,
                                              float* __restrict__ bqkv) {
    int n = blockIdx.x * 256 + threadIdx.x;
    if (n < 2304) {
        const float* s = (n < 768) ? bq : ((n < 1536) ? bk : bv);
        int r = (n < 768) ? n : ((n < 1536) ? n - 768 : n - 1536);
        bqkv[n] = s[r];
    }
}

__global__ __launch_bounds__(256) void k_zero(float* __restrict__ p) {
    p[blockIdx.x * 256 + threadIdx.x] = 0.f;
}

// ---------- GEMM: C[R][N] = A[R][K] * Bt[N][K]^T + bias (+residual) ----------
// XCD-chunked blockIdx swizzle (grid always a multiple of 8).
// SPLIT_VT: blocks with n0>=1536 (V columns) write accumulators TRANSPOSED
// directly into VtG[(col-1536)*Rtot + row] as u16x4 row-runs; normal V write
// is skipped (replaces the k_vtrans pass).
template <bool OUT_BF16, bool ADD_RES, bool SPLIT_VT>
__global__ __launch_bounds__(256) void k_gemm(const u16* __restrict__ A,
                                              const u16* __restrict__ Bt,
                                              const float* __restrict__ bias,
                                              const float* __restrict__ resA,
                                              const float* __restrict__ resB,
                                              void* __restrict__ Cout,
                                              int Ndim, int Kdim, int mvisL,
                                              u16* __restrict__ VtGp, int Rtot) {
    __shared__ alignas(16) u16 sA[128 * 32];
    __shared__ alignas(16) u16 sB[128 * 32];
    const int tid = threadIdx.x, wid = tid >> 6, lane = tid & 63;
    const int nwg = gridDim.x;
    const int wg = (blockIdx.x & 7) * (nwg >> 3) + (blockIdx.x >> 3);
    const int ntiles = Ndim >> 7;
    const int mt = wg / ntiles, nt = wg - mt * ntiles;
    const int m0 = mt << 7, n0 = nt << 7;
    const int wm = wid >> 1, wn = wid & 1;
    f32x4 acc[4][4] = {};

    const int r0 = tid >> 2, p0 = tid & 3;
    const int r1 = 64 + (tid >> 2);
    const u16* ga0 = A + (size_t)(m0 + r0) * Kdim + p0 * 8;
    const u16* ga1 = A + (size_t)(m0 + r1) * Kdim + p0 * 8;
    const u16* gb0 = Bt + (size_t)(n0 + r0) * Kdim + p0 * 8;
    const u16* gb1 = Bt + (size_t)(n0 + r1) * Kdim + p0 * 8;
    u16* lA0 = sA + (wid * 64) * 8;
    u16* lA1 = sA + (256 + wid * 64) * 8;
    u16* lB0 = sB + (wid * 64) * 8;
    u16* lB1 = sB + (256 + wid * 64) * 8;

    const int arow = (wm << 6) + (lane & 15);
    const int brow = (wn << 6) + (lane & 15);
    const int kg = (lane >> 4) * 8;

    for (int kt = 0; kt < Kdim; kt += 32) {
        GLOAD_LDS16(ga0 + kt, lA0);
        GLOAD_LDS16(ga1 + kt, lA1);
        GLOAD_LDS16(gb0 + kt, lB0);
        GLOAD_LDS16(gb1 + kt, lB1);
        __syncthreads();
        bf16x8 av[4], bw[4];
#pragma unroll
        for (int i = 0; i < 4; i++) av[i] = *(const bf16x8*)&sA[(arow + i * 16) * 32 + kg];
#pragma unroll
        for (int j = 0; j < 4; j++) bw[j] = *(const bf16x8*)&sB[(brow + j * 16) * 32 + kg];
#pragma unroll
        for (int i = 0; i < 4; i++)
#pragma unroll
            for (int j = 0; j < 4; j++) acc[i][j] = mfma16(av[i], bw[j], acc[i][j]);
        __syncthreads();
    }

    const int col0 = n0 + (wn << 6) + (lane & 15);
    const int rowb = m0 + (wm << 6) + ((lane >> 4) << 2);
    float bvals[4];
#pragma unroll
    for (int j = 0; j < 4; j++) bvals[j] = bias[col0 + j * 16];

    if constexpr (SPLIT_VT) {
        if (n0 >= 1536) {     // V block: transposed write to VtG, skip normal C
            const int vcol0 = col0 - 1536;
#pragma unroll
            for (int i = 0; i < 4; i++) {
#pragma unroll
                for (int j = 0; j < 4; j++) {
                    u16x4 o4;
#pragma unroll
                    for (int rg = 0; rg < 4; rg++) o4[rg] = f2bf(acc[i][j][rg] + bvals[j]);
                    *(u16x4*)&VtGp[(size_t)(vcol0 + j * 16) * Rtot + rowb + i * 16] = o4;
                }
            }
            return;
        }
    }

#pragma unroll
    for (int i = 0; i < 4; i++) {
#pragma unroll
        for (int rg = 0; rg < 4; rg++) {
            const int row = rowb + i * 16 + rg;
            const float* rp = nullptr;
            if constexpr (ADD_RES)
                rp = (row < mvisL) ? resA + (size_t)row * 768
                                   : resB + (size_t)(row - mvisL) * 768;
#pragma unroll
            for (int j = 0; j < 4; j++) {
                const int col = col0 + j * 16;
                float v = acc[i][j][rg] + bvals[j];
                if constexpr (ADD_RES) v += rp[col];
                if constexpr (OUT_BF16)
                    ((u16*)Cout)[(size_t)row * Ndim + col] = f2bf(v);
                else
                    ((float*)Cout)[(size_t)row * Ndim + col] = v;
            }
        }
    }
}

// ---------- fused cross-attention (exact R7 kernel: best validated, 147us) ----------
// One block per (b,h,direction). 256 q-rows per K/V pass (2 q-sets of 128).
// j-outer QK^T: each K fragment read from LDS once, feeds both q-sets.
// K/V double-buffered, ONE barrier per step, stage(s+1) issued after barrier.
__global__ __launch_bounds__(512) void k_attn(const u16* __restrict__ qkv,
                                              const u16* __restrict__ VtG,
                                              const int* __restrict__ vmaskc,
                                              const int* __restrict__ tmaskc,
                                              u16* __restrict__ attn, int CHn, int Rtot) {
    __shared__ alignas(16) u16 Kl[2][128 * 128];   // 64 KB
    __shared__ alignas(16) u16 Vt[2][96 * 128];    // 48 KB
    __shared__ alignas(16) u16 Pl[8][16 * 128];    // 32 KB
    __shared__ float mk[2][128];

    const int bx = blockIdx.x;
    int b, h, qbase, kbase, nqt, ntl;
    const int* mask;
    const int vcap = CHn * 8;
    if (bx < vcap) {   // visual queries attend to text: 4 passes x 256 rows
        b = bx >> 3; h = bx & 7;
        qbase = b << 10; kbase = (CHn << 10) + (b << 9);
        mask = tmaskc + (b << 9); nqt = 4; ntl = 2;   // ntile=4 (Sk=512)
    } else {           // text queries attend to visual: 2 passes x 256 rows
        const int bx2 = bx - vcap;
        b = bx2 >> 3; h = bx2 & 7;
        qbase = (CHn << 10) + (b << 9); kbase = b << 10;
        mask = vmaskc + (b << 10); nqt = 2; ntl = 3;  // ntile=8 (Sk=1024)
    }
    const int ntile = 1 << ntl;
    const int nsteps = nqt << ntl;
    const int tid = threadIdx.x, wid = tid >> 6, lane = tid & 63;
    const int l15 = lane & 15, l4 = lane >> 4;
    const float scale = 0.10206207261596577f;  // 1/sqrt(96)

    int koff[4];
#pragma unroll
    for (int kk = 0; kk < 4; kk++) koff[kk] = ((kk * 4 + l4) ^ (l15 & 7)) << 3;

    auto kt_of = [&](int s) {
        const int qt = s >> ntl, ktr = s & (ntile - 1);
        return (qt & 1) ? (ntile - 1 - ktr) : ktr;   // serpentine
    };
    auto stage = [&](int kt, int pb) {
#pragma unroll
        for (int it = 0; it < 4; ++it) {             // K tile: 2048 16B chunks
            const int cb = it * 512 + (wid << 6);
            const int c = cb + lane;
            const int r = c >> 4, s8 = c & 15;
            const int k8 = s8 ^ (r & 7);
            const u16* src = qkv + (size_t)(kbase + (kt << 7) + r) * 2304 + 768 + h * 96
                             + (k8 < 12 ? k8 * 8 : 0);
            GLOAD_LDS16(src, &Kl[pb][(size_t)cb * 8]);
        }
#pragma unroll
        for (int it = 0; it < 3; ++it) {             // V tile: 1536 16B chunks
            const int cb = it * 512 + (wid << 6);
            const int c = cb + lane;
            const int d = c >> 4, s8 = c & 15;
            const int k8 = s8 ^ (d & 7);
            const u16* src = VtG + (size_t)(h * 96 + d) * Rtot + kbase + (kt << 7) + k8 * 8;
            GLOAD_LDS16(src, &Vt[pb][(size_t)cb * 8]);
        }
        if (tid < 128) mk[pb][tid] = mask[(kt << 7) + tid] ? 0.f : -1e30f;
    };

    stage(kt_of(0), 0);
    int s = 0;
    for (int qt = 0; qt < nqt; ++qt) {
        bf16x8 aq[2][3];
#pragma unroll
        for (int qs = 0; qs < 2; ++qs) {
            const int qr = qbase + (qt << 8) + (wid << 5) + qs * 16 + l15;
#pragma unroll
            for (int kk = 0; kk < 3; kk++) {
                bf16x8 tq = *(const bf16x8*)&qkv[(size_t)qr * 2304 + h * 96 + kk * 32 + l4 * 8];
#pragma unroll
                for (int e = 0; e < 8; e++) tq[e] = (__bf16)((float)tq[e] * scale);
                aq[qs][kk] = tq;
            }
        }
        f32x4 o[2][6] = {};
        float mrun[2][4], lrun[2][4];
#pragma unroll
        for (int qs = 0; qs < 2; ++qs)
#pragma unroll
            for (int rg = 0; rg < 4; rg++) { mrun[qs][rg] = -1e30f; lrun[qs][rg] = 0.f; }

        for (int ktr = 0; ktr < ntile; ++ktr, ++s) {
            const int cur = s & 1;
            __syncthreads();                      // publish stage(cur); reads of cur^1 done
            if (s + 1 < nsteps) stage(kt_of(s + 1), cur ^ 1);

            // ---- S = Q K^T, j-outer ----
            f32x4 sc[2][8];
#pragma unroll
            for (int j = 0; j < 8; j++) {
                const int rbase = (j * 16 + l15) * 128;
                bf16x8 bk[3];
#pragma unroll
                for (int kk = 0; kk < 3; kk++)
                    bk[kk] = *(const bf16x8*)&Kl[cur][rbase + koff[kk]];
#pragma unroll
                for (int qs = 0; qs < 2; ++qs) {
                    f32x4 cj = {0.f, 0.f, 0.f, 0.f};
#pragma unroll
                    for (int kk = 0; kk < 3; kk++) cj = mfma16(aq[qs][kk], bk[kk], cj);
                    sc[qs][j] = cj;
                }
            }

#pragma unroll
            for (int qs = 0; qs < 2; ++qs) {
                float tmax[4] = {-1e30f, -1e30f, -1e30f, -1e30f};
#pragma unroll
                for (int j = 0; j < 8; j++) {
                    float mb = mk[cur][j * 16 + l15];
#pragma unroll
                    for (int rg = 0; rg < 4; rg++) {
                        float v = sc[qs][j][rg] + mb;
                        sc[qs][j][rg] = v;
                        tmax[rg] = fmaxf(tmax[rg], v);
                    }
                }
#pragma unroll
                for (int d = 1; d < 16; d <<= 1)
#pragma unroll
                    for (int rg = 0; rg < 4; rg++)
                        tmax[rg] = fmaxf(tmax[rg], __shfl_xor(tmax[rg], d));
                int need = 0;
#pragma unroll
                for (int rg = 0; rg < 4; rg++) need |= (tmax[rg] > mrun[qs][rg] + 8.f) ? 1 : 0;
                if (__any(need)) {
#pragma unroll
                    for (int rg = 0; rg < 4; rg++) {
                        float mn = fmaxf(mrun[qs][rg], tmax[rg]);
                        float corr = __expf(mrun[qs][rg] - mn);
                        mrun[qs][rg] = mn;
                        lrun[qs][rg] *= corr;
#pragma unroll
                        for (int j6 = 0; j6 < 6; j6++) o[qs][j6][rg] *= corr;
                    }
                }
                float tsum[4] = {0.f, 0.f, 0.f, 0.f};
#pragma unroll
                for (int j = 0; j < 8; j++)
#pragma unroll
                    for (int rg = 0; rg < 4; rg++) {
                        float p = __expf(sc[qs][j][rg] - mrun[qs][rg]);
                        tsum[rg] += p;
                        const int prow = l4 * 4 + rg;
                        Pl[wid][prow * 128 + ((j * 16 + l15) ^ ((prow & 7) << 3))] = f2bf(p);
                    }
#pragma unroll
                for (int d = 1; d < 16; d <<= 1)
#pragma unroll
                    for (int rg = 0; rg < 4; rg++) tsum[rg] += __shfl_xor(tsum[rg], d);
#pragma unroll
                for (int rg = 0; rg < 4; rg++) lrun[qs][rg] += tsum[rg];

                // ---- O += P V ----
#pragma unroll
                for (int kk = 0; kk < 4; kk++) {
                    bf16x8 ap = *(const bf16x8*)&Pl[wid][l15 * 128 + koff[kk]];
#pragma unroll
                    for (int j6 = 0; j6 < 6; j6++) {
                        bf16x8 bv8 = *(const bf16x8*)&Vt[cur][(j6 * 16 + l15) * 128 + koff[kk]];
                        o[qs][j6] = mfma16(ap, bv8, o[qs][j6]);
                    }
                }
            }
        }

#pragma unroll
        for (int qs = 0; qs < 2; ++qs) {
            float inv[4];
#pragma unroll
            for (int rg = 0; rg < 4; rg++) inv[rg] = 1.f / lrun[qs][rg];
            const size_t orow = (size_t)(qbase + (qt << 8) + (wid << 5) + qs * 16);
#pragma unroll
            for (int j6 = 0; j6 < 6; j6++)
#pragma unroll
                for (int rg = 0; rg < 4; rg++)
                    attn[(orow + l4 * 4 + rg) * 768 + h * 96 + j6 * 16 + l15] =
                        f2bf(o[qs][j6][rg] * inv[rg]);
        }
    }
}

// ---------- LN1 + masked-pool accumulation (bf16 input) ----------
__global__ __launch_bounds__(256) void k_ln_pool(const u16* __restrict__ X,
                                                 const int* __restrict__ vmaskc,
                                                 const int* __restrict__ tmaskc,
                                                 const float* __restrict__ g,
                                                 const float* __restrict__ bb,
                                                 float* __restrict__ pooled,
                                                 int mvisL, int bg0) {
    __shared__ float pool[768];
    const int tid = threadIdx.x, wid = tid >> 6, lane = tid & 63;
    const int row0 = blockIdx.x << 5;
    const bool vis = row0 < mvisL;
    const int* mask = vis ? vmaskc : tmaskc;
    const int mbase = vis ? 0 : mvisL;
    const int bl = vis ? (row0 >> 10) : ((row0 - mvisL) >> 9);
    float* pout = pooled + (vis ? 0 : 12288) + (size_t)(bg0 + bl) * 768;

    float gv[12], bv2[12];
#pragma unroll
    for (int k = 0; k < 12; k++) { gv[k] = g[lane + k * 64]; bv2[k] = bb[lane + k * 64]; }
    float acc[12] = {};
    for (int rr = 0; rr < 8; ++rr) {
        const int row = row0 + (wid << 3) + rr;
        const u16* x = X + (size_t)row * 768;
        float xs[12], sm = 0.f, s2 = 0.f;
#pragma unroll
        for (int k = 0; k < 12; k++) {
            float tv = bf2f(x[lane + k * 64]);
            xs[k] = tv; sm += tv; s2 += tv * tv;
        }
#pragma unroll
        for (int d = 1; d < 64; d <<= 1) { sm += __shfl_xor(sm, d); s2 += __shfl_xor(s2, d); }
        const float mean = sm * (1.f / 768.f);
        const float rstd = rsqrtf(s2 * (1.f / 768.f) - mean * mean + 1e-5f);
        const float mv = (float)mask[row - mbase];
#pragma unroll
        for (int k = 0; k < 12; k++) acc[k] += ((xs[k] - mean) * rstd * gv[k] + bv2[k]) * mv;
    }
    pool[tid] = 0.f; pool[tid + 256] = 0.f; pool[tid + 512] = 0.f;
    __syncthreads();
#pragma unroll
    for (int k = 0; k < 12; k++) atomicAdd(&pool[lane + k * 64], acc[k]);
    __syncthreads();
    atomicAdd(&pout[tid], pool[tid]);
    atomicAdd(&pout[tid + 256], pool[tid + 256]);
    atomicAdd(&pout[tid + 512], pool[tid + 512]);
}

// ---------- final ----------
__device__ __forceinline__ float blk_sum(float v, volatile float* tmp) {
#pragma unroll
    for (int d = 1; d < 64; d <<= 1) v += __shfl_xor(v, d);
    __syncthreads();
    if ((threadIdx.x & 63) == 0) tmp[threadIdx.x >> 6] = v;
    __syncthreads();
    return tmp[0] + tmp[1] + tmp[2] + tmp[3];
}

__global__ __launch_bounds__(256) void k_final(const float* __restrict__ pooled,
                                               const int* __restrict__ vmask,
                                               const int* __restrict__ tmask,
                                               const float* __restrict__ Wf,
                                               const float* __restrict__ bfv,
                                               const float* __restrict__ g2,
                                               const float* __restrict__ b2,
                                               float* __restrict__ out) {
    __shared__ float sh[1536];
    __shared__ float red[4];
    const int b = blockIdx.x, tid = threadIdx.x;
    float cv = 0.f, ct = 0.f;
    for (int i = tid; i < 1024; i += 256) cv += (float)vmask[(b << 10) + i];
    for (int i = tid; i < 512; i += 256) ct += (float)tmask[(b << 9) + i];
    cv = blk_sum(cv, red);
    ct = blk_sum(ct, red);
    const float iv = 1.f / cv, itv = 1.f / ct;
#pragma unroll
    for (int k = 0; k < 3; k++) {
        int j = tid + (k << 8);
        sh[j] = pooled[b * 768 + j] * iv;
        sh[768 + j] = pooled[12288 + b * 768 + j] * itv;
    }
    __syncthreads();
    float f0 = bfv[tid], f1 = bfv[tid + 256], f2 = bfv[tid + 512];
    for (int i = 0; i < 1536; i++) {
        const float pv = sh[i];
        const float* w = Wf + (size_t)i * 768;
        f0 += pv * w[tid];
        f1 += pv * w[tid + 256];
        f2 += pv * w[tid + 512];
    }
    float sm = blk_sum(f0 + f1 + f2, red);
    float s2 = blk_sum(f0 * f0 + f1 * f1 + f2 * f2, red);
    const float mean = sm * (1.f / 768.f);
    const float rstd = rsqrtf(s2 * (1.f / 768.f) - mean * mean + 1e-5f);
    out[b * 768 + tid] = (f0 - mean) * rstd * g2[tid] + b2[tid];
    out[b * 768 + tid + 256] = (f1 - mean) * rstd * g2[tid + 256] + b2[tid + 256];
    out[b * 768 + tid + 512] = (f2 - mean) * rstd * g2[tid + 512] + b2[tid + 512];
}

// ---------- host ----------
extern "C" void kernel_launch(void* const* d_in, const int* in_sizes, int n_in,
                              void* d_out, int out_size, void* d_ws, size_t ws_size,
                              hipStream_t stream) {
    (void)in_sizes; (void)n_in; (void)out_size;
    const float* vf = (const float*)d_in[0];
    const float* tf = (const float*)d_in[1];
    const int* vmask = (const int*)d_in[2];
    const int* tmask = (const int*)d_in[3];
    const float* Wq = (const float*)d_in[4];
    const float* bq = (const float*)d_in[5];
    const float* Wk = (const float*)d_in[6];
    const float* bk = (const float*)d_in[7];
    const float* Wv = (const float*)d_in[8];
    const float* bv = (const float*)d_in[9];
    const float* Wo = (const float*)d_in[10];
    const float* bo = (const float*)d_in[11];
    const float* g1 = (const float*)d_in[12];
    const float* b1 = (const float*)d_in[13];
    const float* Wf = (const float*)d_in[14];
    const float* bfv = (const float*)d_in[15];
    const float* g2 = (const float*)d_in[16];
    const float* b2 = (const float*)d_in[17];
    float* outp = (float*)d_out;

    // footprint = 4,826,112 + CH * (2,359,296 X + 7,077,888 QKV + 2,359,296 VtG)
    int CH = 16;
    while (CH > 1 && 4826112ull + (size_t)CH * 11796480ull > ws_size) CH >>= 1;
    const int NC = 16 / CH;
    const int Rtot = CH * 1536;

    char* ws = (char*)d_ws;
    u16*   wsW      = (u16*)(ws);
    u16*   wsWo     = (u16*)(ws + 3538944);
    float* wsBqkv   = (float*)(ws + 4718592);
    float* wsPooled = (float*)(ws + 4727808);
    u16*   wsX      = (u16*)(ws + 4826112);                 // [R][768] bf16 (reused: attn out)
    char*  qkvBase  = ws + 4826112 + (size_t)CH * 2359296;
    u16*   wsQKV    = (u16*)qkvBase;                         // [R][2304] bf16 (reused: Oproj bf16)
    u16*   wsOproj  = (u16*)qkvBase;
    u16*   wsVtG    = (u16*)(qkvBase + (size_t)CH * 7077888);// [768][R] bf16
    u16*   wsAttn   = wsX;

    k_transpose<<<dim3(144), dim3(256), 0, stream>>>(Wq, wsW, 768, 768);
    k_transpose<<<dim3(144), dim3(256), 0, stream>>>(Wk, wsW + 589824, 768, 768);
    k_transpose<<<dim3(144), dim3(256), 0, stream>>>(Wv, wsW + 1179648, 768, 768);
    k_transpose<<<dim3(144), dim3(256), 0, stream>>>(Wo, wsWo, 768, 768);
    k_bias<<<dim3(9), dim3(256), 0, stream>>>(bq, bk, bv, wsBqkv);
    k_zero<<<dim3(96), dim3(256), 0, stream>>>(wsPooled);

    for (int c = 0; c < NC; ++c) {
        const float* vfc = vf + (size_t)c * CH * 1024 * 768;
        const float* tfc = tf + (size_t)c * CH * 512 * 768;
        const int* vmc = vmask + c * CH * 1024;
        const int* tmc = tmask + c * CH * 512;

        k_cvt_x<<<dim3(CH * 1152), dim3(256), 0, stream>>>(vfc, tfc, wsX, CH * 196608);

        // QKV GEMM; V third written transposed directly into VtG (k_vtrans removed)
        k_gemm<true, false, true><<<dim3(CH * 216), dim3(256), 0, stream>>>(
            wsX, wsW, wsBqkv, nullptr, nullptr, (void*)wsQKV, 2304, 768, 0, wsVtG, Rtot);

        k_attn<<<dim3(CH * 16), dim3(512), 0, stream>>>(
            wsQKV, wsVtG, vmc, tmc, wsAttn, CH, Rtot);

        // O-proj + bias + residual, bf16 out
        k_gemm<true, true, false><<<dim3(CH * 72), dim3(256), 0, stream>>>(
            wsAttn, wsWo, bo, vfc, tfc, (void*)wsOproj, 768, 768, CH * 1024, nullptr, 0);

        k_ln_pool<<<dim3(CH * 48), dim3(256), 0, stream>>>(
            wsOproj, vmc, tmc, g1, b1, wsPooled, CH * 1024, c * CH);
    }

    k_final<<<dim3(16), dim3(256), 0, stream>>>(wsPooled, vmask, tmask, Wf, bfv, g2, b2, outp);
}